// Round 26
// baseline (2272.141 us; speedup 1.0000x reference)
//
#include <hip/hip_runtime.h>
#include <hip/hip_bf16.h>
#include <math.h>

namespace {

constexpr int Bc  = 8;
constexpr int Lc  = 2048;
constexpr int VOC = 1969;
constexpr int VOCP = 2048;            // padded vocab rows for logits GEMM
constexpr int DM  = 768;
constexpr int DI  = 1536;
constexpr int DS  = 16;
constexpr int DC  = 4;
constexpr int DR  = 48;
constexpr int M   = Bc * Lc;          // 16384 rows
constexpr int NC  = 16;               // scan chunks (R26: 32 -> 16; halves scan2 chain
                                      // + per-chunk overhead; CT-loop body is cheap
                                      // post exp-chain fast path)
constexpr int CT  = Lc / NC;          // 128 timesteps per chunk
constexpr float EPS_ = 1e-5f;

typedef __bf16 bf16x8 __attribute__((ext_vector_type(8)));
typedef float  f32x4  __attribute__((ext_vector_type(4)));

__device__ __forceinline__ float siluf(float x) { return x / (1.f + __expf(-x)); }
__device__ __forceinline__ float softplusf(float x) {
  return (x > 20.f) ? x : __logf(1.f + __expf(x));
}

#define GLOAD16(gp, lp)                                                        \
  __builtin_amdgcn_global_load_lds(                                            \
      (const __attribute__((address_space(1))) void*)(gp),                     \
      (__attribute__((address_space(3))) void*)(lp), 16, 0, 0)

// -------- f32 -> bf16 conversion (packed) --------
__global__ __launch_bounds__(256) void k_f2b(const float* __restrict__ in,
                                             __bf16* __restrict__ out, int n4) {
  for (int i = blockIdx.x * 256 + threadIdx.x; i < n4; i += gridDim.x * 256) {
    float4 v = *(const float4*)(in + (size_t)i * 4);
    __bf16* o = out + (size_t)i * 4;
    o[0] = (__bf16)v.x; o[1] = (__bf16)v.y; o[2] = (__bf16)v.z; o[3] = (__bf16)v.w;
  }
}

// f32 -> bf16 with per-layer row/col zero-padding.
__global__ __launch_bounds__(256) void k_f2b_pad(const float* __restrict__ in,
                                                 __bf16* __restrict__ out,
                                                 int layers, int rin, int rout,
                                                 int cin, int cout) {
  size_t total = (size_t)layers * rout * cout;
  for (size_t i = (size_t)blockIdx.x * 256 + threadIdx.x; i < total;
       i += (size_t)gridDim.x * 256) {
    int lay = (int)(i / ((size_t)rout * cout));
    int rem = (int)(i % ((size_t)rout * cout));
    int r = rem / cout, c = rem % cout;
    float v = (r < rin && c < cin) ? in[((size_t)lay * rin + r) * cin + c] : 0.f;
    out[i] = (__bf16)v;
  }
}

// h[row,d] = embed[ids[row]][d] + times[row]*time_w[d] + time_b[d]   (bf16 h)
__global__ void k_embed(const int* __restrict__ ids, const float* __restrict__ times,
                        const float* __restrict__ emb, const float* __restrict__ tw,
                        const float* __restrict__ tb, __bf16* __restrict__ h) {
  int row = blockIdx.x;
  int id  = ids[row];
  float tv = times[row];
  const float* e = emb + (size_t)id * DM;
  for (int d = threadIdx.x; d < DM; d += blockDim.x)
    h[(size_t)row * DM + d] = (__bf16)(e[d] + tv * tw[d] + tb[d]);
}

// bf16 in/out: o[row,:] = h[row,:] * rsqrt(mean(h^2)+eps) * w
__global__ __launch_bounds__(256) void k_rmsnorm(const __bf16* __restrict__ x,
                                                 const float* __restrict__ w,
                                                 __bf16* __restrict__ o) {
  int row = blockIdx.x;
  const __bf16* xr = x + (size_t)row * DM;
  float v[3];
  float s = 0.f;
#pragma unroll
  for (int i = 0; i < 3; i++) { v[i] = (float)xr[threadIdx.x + 256 * i]; s += v[i] * v[i]; }
#pragma unroll
  for (int off = 32; off > 0; off >>= 1) s += __shfl_down(s, off);
  __shared__ float red[4];
  int lane = threadIdx.x & 63, wv = threadIdx.x >> 6;
  if (lane == 0) red[wv] = s;
  __syncthreads();
  if (threadIdx.x == 0)
    red[0] = rsqrtf((red[0] + red[1] + red[2] + red[3]) / (float)DM + EPS_);
  __syncthreads();
  float sc = red[0];
#pragma unroll
  for (int i = 0; i < 3; i++) {
    int d = threadIdx.x + 256 * i;
    o[(size_t)row * DM + d] = (__bf16)(v[i] * sc * w[d]);
  }
}

// Depthwise causal conv (width 4) + bias + silu ; bf16x8 vectorized, dense [M][DI].
__global__ __launch_bounds__(256) void k_conv8(const __bf16* __restrict__ xb,
                                               const float* __restrict__ cwt,
                                               const float* __restrict__ cbv,
                                               __bf16* __restrict__ xo) {
  size_t idx = (size_t)blockIdx.x * 256 + threadIdx.x;   // < M*DI/8
  int dg = (int)(idx % (DI / 8));
  size_t row = idx / (DI / 8);
  int d0 = dg * 8;
  int t = (int)(row % Lc);
  size_t b = row / Lc;
  float acc[8];
  float4 cwv[8];
#pragma unroll
  for (int j = 0; j < 8; j++) {
    acc[j] = cbv[d0 + j];
    cwv[j] = *(const float4*)(cwt + (d0 + j) * DC);
  }
#pragma unroll
  for (int tap = 0; tap < DC; tap++) {
    int tt = t - (DC - 1) + tap;
    if (tt >= 0) {
      bf16x8 v = *(const bf16x8*)(xb + ((size_t)b * Lc + tt) * DI + d0);
#pragma unroll
      for (int j = 0; j < 8; j++) {
        float wt = (tap == 0) ? cwv[j].x : (tap == 1) ? cwv[j].y
                   : (tap == 2) ? cwv[j].z : cwv[j].w;
        acc[j] += wt * (float)v[j];
      }
    }
  }
  bf16x8 o;
#pragma unroll
  for (int j = 0; j < 8; j++) o[j] = (__bf16)siluf(acc[j]);
  *(bf16x8*)(xo + idx * 8) = o;
}

// ------ bf16 MFMA GEMM: 128x256 tile, BK=32, 512 threads, 2-phase LDS dbuf ------
// Session-converged optimum (see R24 notes); unchanged this round.
__global__ __launch_bounds__(512) void k_gemm_mfma(
    const __bf16* __restrict__ A, int lda,
    const __bf16* __restrict__ W, int ldw,
    const float* __restrict__ bias,
    float* __restrict__ Cf, __bf16* __restrict__ Cb, int ldc,
    int N, int K, int act, int resAdd,
    __bf16* __restrict__ Cb2, int Nsplit) {
  constexpr int BUFE = 12288;           // A 4096 + B 8192 elements per buffer
  __shared__ __bf16 lds[2 * BUFE];      // 48 KB
  int tid = threadIdx.x;
  int l = tid & 63, w = tid >> 6;       // 8 waves
  int wr = w >> 2, wc = w & 3;          // 2 M-halves x 4 N-quarters

  // L2-aware sub-chunked remap: XCD (lin&7) owns bm-blocks [xcd*cm, xcd*cm+cm);
  // within it, iterate all bn for 4 bm-blocks at a time (A sub-panel 1.18MB).
  int gm = gridDim.x;                   // # of 128-row bm blocks
  int nb = gridDim.y;                   // # of 256-col bn blocks
  int lin = blockIdx.y * gm + blockIdx.x;
  int cm = gm >> 3;                     // bm-blocks per XCD chunk (16)
  int xcd = lin & 7;
  int r = lin >> 3;                     // [0, cm*nb)
  int subi = r / (nb << 2);             // sub-chunk index (cm/4 of them)
  int rem  = r % (nb << 2);
  int bni  = rem >> 2;
  int bmj  = rem & 3;
  int bm = (xcd * cm + subi * 4 + bmj) << 7;
  int bn = bni << 8;                    // 256-wide N tiles

  // --- staging: A 512 chunks (1/thread), B 1024 chunks (2/thread); 16B each.
  int ra0 = 16 * w + (l >> 2);
  int rb0 = ra0;
  int rb1 = 128 + ra0;
  int sa0 = ((l & 3) - ra0 - (ra0 >> 2)) & 3;   // pre-permuted global k-slot
  int sb0 = sa0;
  int sb1 = ((l & 3) - rb1 - (rb1 >> 2)) & 3;
  const char* gA0 = (const char*)(A + (size_t)(bm + ra0) * lda) + sa0 * 16;
  const char* gB0 = (const char*)(W + (size_t)(bn + rb0) * ldw) + sb0 * 16;
  const char* gB1 = (const char*)(W + (size_t)(bn + rb1) * ldw) + sb1 * 16;
  int lA0 = (16 * w) * 32;                      // element offsets inside a buffer
  int lB0 = 4096 + (16 * w) * 32;
  int lB1 = 4096 + (128 + 16 * w) * 32;

  int aoff[4], boff[4];
#pragma unroll
  for (int i = 0; i < 4; i++) {
    int ra = wr * 64 + i * 16 + (l & 15);
    aoff[i] = ra * 32 + ((((l >> 4) + ra + (ra >> 2)) & 3) << 3);
    int rb = wc * 64 + i * 16 + (l & 15);
    boff[i] = 4096 + rb * 32 + ((((l >> 4) + rb + (rb >> 2)) & 3) << 3);
  }

  f32x4 acc[4][4];
#pragma unroll
  for (int i = 0; i < 4; i++)
#pragma unroll
    for (int j = 0; j < 4; j++)
#pragma unroll
      for (int e = 0; e < 4; e++) acc[i][j][e] = 0.f;

#define STAGE(t)                                                               \
  do {                                                                         \
    __bf16* Lb_ = lds + ((t) & 1) * BUFE;                                      \
    size_t kb_ = (size_t)(t) * 64;                                             \
    GLOAD16(gA0 + kb_, Lb_ + lA0);                                             \
    GLOAD16(gB0 + kb_, Lb_ + lB0);                                             \
    GLOAD16(gB1 + kb_, Lb_ + lB1);                                             \
  } while (0)

  int NT = K >> 5;
  STAGE(0);
  __syncthreads();                      // drain tile 0

  for (int t = 0; t < NT; ++t) {
    if (t + 1 < NT) STAGE(t + 1);       // async: in flight during compute of tile t
    const __bf16* Lb = lds + (t & 1) * BUFE;
    bf16x8 af[4], bfr[4];
#pragma unroll
    for (int i = 0; i < 4; i++) {
      af[i]  = *(const bf16x8*)(Lb + aoff[i]);
      bfr[i] = *(const bf16x8*)(Lb + boff[i]);
    }
    __builtin_amdgcn_s_setprio(1);
#pragma unroll
    for (int i = 0; i < 4; i++)
#pragma unroll
      for (int j = 0; j < 4; j++)
        acc[i][j] = __builtin_amdgcn_mfma_f32_16x16x32_bf16(af[i], bfr[j], acc[i][j], 0, 0, 0);
    __builtin_amdgcn_s_setprio(0);
    __syncthreads();                    // drains stage(t+1) + barrier (one per tile)
  }
#undef STAGE

#pragma unroll
  for (int i = 0; i < 4; i++) {
#pragma unroll
    for (int r2 = 0; r2 < 4; r2++) {
      int grow = bm + wr * 64 + i * 16 + (l >> 4) * 4 + r2;
#pragma unroll
      for (int j = 0; j < 4; j++) {
        int gcol = bn + wc * 64 + j * 16 + (l & 15);
        if (gcol < N) {
          float v = acc[i][j][r2];
          if (bias) v += bias[gcol];
          if (act == 1) v = softplusf(v);
          size_t off = (size_t)grow * ldc + gcol;
          if (Cb2) {
            if (gcol < Nsplit) Cb[off] = (__bf16)v;
            else               Cb2[(size_t)grow * ldc + (gcol - Nsplit)] = (__bf16)v;
          } else if (Cb) {
            if (resAdd) Cb[off] = (__bf16)((float)Cb[off] + v);
            else        Cb[off] = (__bf16)v;
          } else if (resAdd) {
            Cf[off] += v;
          } else {
            Cf[off] = v;
          }
        }
      }
    }
  }
}

// ---------------- chunked selective scan ----------------
// sc is bf16: [h0..h15 | P0..P15] per (b,c,d).  A_log fast path: Av[n] = -(n+1)
// (detected per-thread, exact fallback otherwise).
__global__ __launch_bounds__(256) void k_scan1(
    const __bf16* __restrict__ dlt,
    const __bf16* __restrict__ u_xc,
    const __bf16* __restrict__ xdbl,
    const float* __restrict__ alog,
    __bf16* __restrict__ sc) {
  __shared__ float bcs[CT][32];
  int b = blockIdx.z, c = blockIdx.y;
  int d = blockIdx.x * 256 + threadIdx.x;
  int row0 = b * Lc + c * CT;
#pragma unroll
  for (int k = 0; k < (CT * 32) / 256; k++) {
    int i = k * 256 + threadIdx.x;
    int t = i >> 5, j = i & 31;
    bcs[t][j] = (float)xdbl[(size_t)(row0 + t) * 80 + 48 + j];
  }
  float Av[16];
#pragma unroll
  for (int n = 0; n < 16; n++) Av[n] = -__expf(alog[d * DS + n]);
  bool fast = true;
#pragma unroll
  for (int n = 0; n < 16; n++) fast = fast && (fabsf(Av[n] + (float)(n + 1)) < 1e-4f);
  float h[16], P[16];
#pragma unroll
  for (int n = 0; n < 16; n++) { h[n] = 0.f; P[n] = 1.f; }
  float S = 0.f;
  __syncthreads();
  if (fast) {
    for (int t = 0; t < CT; t++) {
      size_t row = row0 + t;
      float dl = (float)dlt[row * DI + d];
      float u  = (float)u_xc[row * DI + d];
      float du = dl * u;
      float e[16];
      e[0] = __expf(-dl);
#pragma unroll
      for (int n = 1; n < 16; n++) e[n] = e[n - 1] * e[0];
#pragma unroll
      for (int n = 0; n < 16; n++) h[n] = h[n] * e[n] + du * bcs[t][n];
      S += dl;
    }
    P[0] = __expf(-S);
#pragma unroll
    for (int n = 1; n < 16; n++) P[n] = P[n - 1] * P[0];
  } else {
    for (int t = 0; t < CT; t++) {
      size_t row = row0 + t;
      float dl = (float)dlt[row * DI + d];
      float u  = (float)u_xc[row * DI + d];
      float du = dl * u;
#pragma unroll
      for (int n = 0; n < 16; n++) {
        float e = __expf(dl * Av[n]);
        h[n] = h[n] * e + du * bcs[t][n];
        P[n] *= e;
      }
    }
  }
  __bf16* o = sc + (((size_t)b * NC + c) * DI + d) * 32;
  bf16x8 v0, v1, v2, v3;
#pragma unroll
  for (int n = 0; n < 8; n++) { v0[n] = (__bf16)h[n]; v1[n] = (__bf16)h[8 + n];
                                v2[n] = (__bf16)P[n]; v3[n] = (__bf16)P[8 + n]; }
  *(bf16x8*)(o)      = v0;
  *(bf16x8*)(o + 8)  = v1;
  *(bf16x8*)(o + 16) = v2;
  *(bf16x8*)(o + 24) = v3;
}

__global__ __launch_bounds__(256) void k_scan2(__bf16* __restrict__ sc) {
  int g = blockIdx.x * 256 + threadIdx.x;
  int n = g & 15;
  int rest = g >> 4;
  int d = rest % DI;
  int b = rest / DI;
  float cur = 0.f;
  for (int c = 0; c < NC; c++) {
    __bf16* p = sc + (((size_t)b * NC + c) * DI + d) * 32;
    float hf = (float)p[n];
    float pd = (float)p[16 + n];
    p[n] = (__bf16)cur;
    cur = pd * cur + hf;
  }
}

__global__ __launch_bounds__(256) void k_scan3(
    const __bf16* __restrict__ dlt,
    const __bf16* __restrict__ zb,
    __bf16* __restrict__ u_xc,          // in: u, out: y*silu(z)
    const __bf16* __restrict__ xdbl,
    const float* __restrict__ alog,
    const float* __restrict__ dsk,
    const __bf16* __restrict__ sc) {
  __shared__ float bcs[CT][32];
  int b = blockIdx.z, c = blockIdx.y;
  int d = blockIdx.x * 256 + threadIdx.x;
  int row0 = b * Lc + c * CT;
#pragma unroll
  for (int k = 0; k < (CT * 32) / 256; k++) {
    int i = k * 256 + threadIdx.x;
    int t = i >> 5, j = i & 31;
    bcs[t][j] = (float)xdbl[(size_t)(row0 + t) * 80 + 48 + j];
  }
  float Av[16];
#pragma unroll
  for (int n = 0; n < 16; n++) Av[n] = -__expf(alog[d * DS + n]);
  bool fast = true;
#pragma unroll
  for (int n = 0; n < 16; n++) fast = fast && (fabsf(Av[n] + (float)(n + 1)) < 1e-4f);
  float Dv = dsk[d];
  float h[16];
  const __bf16* ip = sc + (((size_t)b * NC + c) * DI + d) * 32;
  {
    bf16x8 v0 = *(const bf16x8*)(ip);
    bf16x8 v1 = *(const bf16x8*)(ip + 8);
#pragma unroll
    for (int n = 0; n < 8; n++) { h[n] = (float)v0[n]; h[8 + n] = (float)v1[n]; }
  }
  __syncthreads();
  if (fast) {
    for (int t = 0; t < CT; t++) {
      size_t row = row0 + t;
      float dl = (float)dlt[row * DI + d];
      float u  = (float)u_xc[row * DI + d];
      float du = dl * u;
      float e[16];
      e[0] = __expf(-dl);
#pragma unroll
      for (int n = 1; n < 16; n++) e[n] = e[n - 1] * e[0];
      float y = 0.f;
#pragma unroll
      for (int n = 0; n < 16; n++) {
        h[n] = h[n] * e[n] + du * bcs[t][n];
        y += h[n] * bcs[t][16 + n];
      }
      y += u * Dv;
      float z = (float)zb[row * DI + d];
      u_xc[row * DI + d] = (__bf16)(y * siluf(z));
    }
  } else {
    for (int t = 0; t < CT; t++) {
      size_t row = row0 + t;
      float dl = (float)dlt[row * DI + d];
      float u  = (float)u_xc[row * DI + d];
      float du = dl * u;
      float y = 0.f;
#pragma unroll
      for (int n = 0; n < 16; n++) {
        float e = __expf(dl * Av[n]);
        h[n] = h[n] * e + du * bcs[t][n];
        y += h[n] * bcs[t][16 + n];
      }
      y += u * Dv;
      float z = (float)zb[row * DI + d];
      u_xc[row * DI + d] = (__bf16)(y * siluf(z));
    }
  }
}

}  // namespace

extern "C" void kernel_launch(void* const* d_in, const int* in_sizes, int n_in,
                              void* d_out, int out_size, void* d_ws, size_t ws_size,
                              hipStream_t stream) {
  const int*   ids   = (const int*)d_in[0];
  const float* times = (const float*)d_in[1];
  const float* emb   = (const float*)d_in[3];
  const float* tw    = (const float*)d_in[4];
  const float* tb    = (const float*)d_in[5];
  const float* inw   = (const float*)d_in[6];
  const float* cw    = (const float*)d_in[7];
  const float* cb    = (const float*)d_in[8];
  const float* xw    = (const float*)d_in[9];
  const float* dtw   = (const float*)d_in[10];
  const float* dtb   = (const float*)d_in[11];
  const float* alog  = (const float*)d_in[12];
  const float* dsk   = (const float*)d_in[13];
  const float* ow    = (const float*)d_in[14];
  const float* nw    = (const float*)d_in[15];
  const float* nfw   = (const float*)d_in[16];
  float* out = (float*)d_out;

  // ---- workspace layout (bf16; 16B aligned) ----
  __bf16* wsb = (__bf16*)d_ws;
  __bf16* hb    = wsb;  wsb += (size_t)M * DM;               // 25.2 MB (bf16 residual)
  __bf16* hnb   = wsb;  wsb += (size_t)M * DM;               // 25.2 MB
  __bf16* xb    = wsb;  wsb += (size_t)M * DI;               // 50.3 MB
  __bf16* zbuf  = wsb;  wsb += (size_t)M * DI;               // 50.3 MB
  __bf16* xcb   = wsb;  wsb += (size_t)M * DI;               // 50.3 MB
  __bf16* dltb  = wsb;  wsb += (size_t)M * DI;               // 50.3 MB (bf16 delta)
  __bf16* scb   = wsb;  wsb += (size_t)Bc * NC * DI * 32;    // 12.6 MB (bf16 chunk states)
  __bf16* xdblb = wsb;  wsb += (size_t)M * 80;               // 2.6 MB
  __bf16* ebw   = wsb;  wsb += (size_t)VOCP * DM;            // 3.1 MB
  __bf16* inwb  = wsb;  wsb += (size_t)4 * 2 * DI * DM;      // 18.9 MB
  __bf16* xwb   = wsb;  wsb += (size_t)4 * 256 * DI;         // 3.1 MB (80->256 rows)
  __bf16* owb   = wsb;  wsb += (size_t)4 * DM * DI;          // 9.4 MB
  __bf16* dtwb  = wsb;  wsb += (size_t)4 * DI * 64;          // 0.8 MB

  // weight / embed conversions (every call; deterministic)
  k_f2b<<<2048, 256, 0, stream>>>(inw, inwb, (4 * 2 * DI * DM) / 4);
  k_f2b<<<2048, 256, 0, stream>>>(ow,  owb,  (4 * DM * DI) / 4);
  k_f2b_pad<<<2048, 256, 0, stream>>>(emb, ebw, 1, VOC, VOCP, DM, DM);
  k_f2b_pad<<<2048, 256, 0, stream>>>(xw,  xwb, 4, 80, 256, DI, DI);
  k_f2b_pad<<<1024, 256, 0, stream>>>(dtw, dtwb, 4, DI, DI, DR, 64);

  k_embed<<<M, 256, 0, stream>>>(ids, times, emb, tw, tb, hb);

  for (int i = 0; i < 4; i++) {
    k_rmsnorm<<<M, 256, 0, stream>>>(hb, nw + i * DM, hnb);
    {  // [x | z] = hn @ in_proj^T  (ONE dispatch, split bf16 outputs xb / zbuf)
      dim3 g(M / 128, (2 * DI) / 256);
      k_gemm_mfma<<<g, 512, 0, stream>>>(hnb, DM, inwb + (size_t)i * 2 * DI * DM, DM,
                                         nullptr, nullptr, xb, DI, 2 * DI, DM, 0, 0,
                                         zbuf, DI);
    }
    {  // xcb = silu(conv1d(x) + cb)   (vectorized, 8 d's per thread)
      int blocks = (int)(((size_t)M * DI / 8) / 256);
      k_conv8<<<blocks, 256, 0, stream>>>(xb, cw + i * DI * DC, cb + i * DI, xcb);
    }
    {  // xdbl = u @ x_proj^T  (bf16 out, N=80, weights padded to 256 rows)
      dim3 g(M / 128, 1);
      k_gemm_mfma<<<g, 512, 0, stream>>>(xcb, DI, xwb + (size_t)i * 256 * DI, DI,
                                         nullptr, nullptr, xdblb, 80, 80, DI, 0, 0,
                                         nullptr, 0);
    }
    {  // delta = softplus(xdbl @ dtw_pad^T + dtb)  -> bf16 (K=64)
      dim3 g(M / 128, DI / 256);
      k_gemm_mfma<<<g, 512, 0, stream>>>(xdblb, 80, dtwb + (size_t)i * DI * 64, 64,
                                         dtb + i * DI, nullptr, dltb, DI, DI, 64, 1, 0,
                                         nullptr, 0);
    }
    {  // chunked selective scan + y*silu(z), in place over xcb
      dim3 g1(DI / 256, NC, Bc);
      k_scan1<<<g1, 256, 0, stream>>>(dltb, xcb, xdblb, alog + (size_t)i * DI * DS, scb);
      k_scan2<<<(Bc * DI * DS) / 256, 256, 0, stream>>>(scb);
      k_scan3<<<g1, 256, 0, stream>>>(dltb, zbuf, xcb, xdblb,
                                      alog + (size_t)i * DI * DS, dsk + i * DI, scb);
    }
    {  // h += y @ out_proj^T   (bf16 RMW resAdd)
      dim3 g(M / 128, DM / 256);
      k_gemm_mfma<<<g, 512, 0, stream>>>(xcb, DI, owb + (size_t)i * DM * DI, DI,
                                         nullptr, nullptr, hb, DM, DM, DI, 0, 1,
                                         nullptr, 0);
    }
  }

  k_rmsnorm<<<M, 256, 0, stream>>>(hb, nfw, hnb);
  {  // logits = hn @ embed^T   (N=1969, padded rows, f32 out)
    dim3 g(M / 128, VOCP / 256);
    k_gemm_mfma<<<g, 512, 0, stream>>>(hnb, DM, ebw, DM,
                                       nullptr, out, nullptr, VOC, VOC, DM, 0, 0,
                                       nullptr, 0);
  }
}

// Round 27
// 2193.592 us; speedup vs baseline: 1.0358x; 1.0358x over previous
//
#include <hip/hip_runtime.h>
#include <hip/hip_bf16.h>
#include <math.h>

namespace {

constexpr int Bc  = 8;
constexpr int Lc  = 2048;
constexpr int VOC = 1969;
constexpr int VOCP = 2048;            // padded vocab rows for logits GEMM
constexpr int DM  = 768;
constexpr int DI  = 1536;
constexpr int DS  = 16;
constexpr int DC  = 4;
constexpr int DR  = 48;
constexpr int M   = Bc * Lc;          // 16384 rows
constexpr int NC  = 32;               // scan chunks (measured optimum: NC=16 cost
                                      // scan TLP and regressed +80us in R26)
constexpr int CT  = Lc / NC;          // 64 timesteps per chunk
constexpr float EPS_ = 1e-5f;

typedef __bf16 bf16x8 __attribute__((ext_vector_type(8)));
typedef float  f32x4  __attribute__((ext_vector_type(4)));

__device__ __forceinline__ float siluf(float x) { return x / (1.f + __expf(-x)); }
__device__ __forceinline__ float softplusf(float x) {
  return (x > 20.f) ? x : __logf(1.f + __expf(x));
}

#define GLOAD16(gp, lp)                                                        \
  __builtin_amdgcn_global_load_lds(                                            \
      (const __attribute__((address_space(1))) void*)(gp),                     \
      (__attribute__((address_space(3))) void*)(lp), 16, 0, 0)

// -------- f32 -> bf16 conversion (packed) --------
__global__ __launch_bounds__(256) void k_f2b(const float* __restrict__ in,
                                             __bf16* __restrict__ out, int n4) {
  for (int i = blockIdx.x * 256 + threadIdx.x; i < n4; i += gridDim.x * 256) {
    float4 v = *(const float4*)(in + (size_t)i * 4);
    __bf16* o = out + (size_t)i * 4;
    o[0] = (__bf16)v.x; o[1] = (__bf16)v.y; o[2] = (__bf16)v.z; o[3] = (__bf16)v.w;
  }
}

// f32 -> bf16 with per-layer row/col zero-padding.
__global__ __launch_bounds__(256) void k_f2b_pad(const float* __restrict__ in,
                                                 __bf16* __restrict__ out,
                                                 int layers, int rin, int rout,
                                                 int cin, int cout) {
  size_t total = (size_t)layers * rout * cout;
  for (size_t i = (size_t)blockIdx.x * 256 + threadIdx.x; i < total;
       i += (size_t)gridDim.x * 256) {
    int lay = (int)(i / ((size_t)rout * cout));
    int rem = (int)(i % ((size_t)rout * cout));
    int r = rem / cout, c = rem % cout;
    float v = (r < rin && c < cin) ? in[((size_t)lay * rin + r) * cin + c] : 0.f;
    out[i] = (__bf16)v;
  }
}

// h[row,d] = embed[ids[row]][d] + times[row]*time_w[d] + time_b[d]   (bf16 h)
__global__ void k_embed(const int* __restrict__ ids, const float* __restrict__ times,
                        const float* __restrict__ emb, const float* __restrict__ tw,
                        const float* __restrict__ tb, __bf16* __restrict__ h) {
  int row = blockIdx.x;
  int id  = ids[row];
  float tv = times[row];
  const float* e = emb + (size_t)id * DM;
  for (int d = threadIdx.x; d < DM; d += blockDim.x)
    h[(size_t)row * DM + d] = (__bf16)(e[d] + tv * tw[d] + tb[d]);
}

// bf16 in/out: o[row,:] = h[row,:] * rsqrt(mean(h^2)+eps) * w
__global__ __launch_bounds__(256) void k_rmsnorm(const __bf16* __restrict__ x,
                                                 const float* __restrict__ w,
                                                 __bf16* __restrict__ o) {
  int row = blockIdx.x;
  const __bf16* xr = x + (size_t)row * DM;
  float v[3];
  float s = 0.f;
#pragma unroll
  for (int i = 0; i < 3; i++) { v[i] = (float)xr[threadIdx.x + 256 * i]; s += v[i] * v[i]; }
#pragma unroll
  for (int off = 32; off > 0; off >>= 1) s += __shfl_down(s, off);
  __shared__ float red[4];
  int lane = threadIdx.x & 63, wv = threadIdx.x >> 6;
  if (lane == 0) red[wv] = s;
  __syncthreads();
  if (threadIdx.x == 0)
    red[0] = rsqrtf((red[0] + red[1] + red[2] + red[3]) / (float)DM + EPS_);
  __syncthreads();
  float sc = red[0];
#pragma unroll
  for (int i = 0; i < 3; i++) {
    int d = threadIdx.x + 256 * i;
    o[(size_t)row * DM + d] = (__bf16)(v[i] * sc * w[d]);
  }
}

// Depthwise causal conv (width 4) + bias + silu ; bf16x8 vectorized, dense [M][DI].
__global__ __launch_bounds__(256) void k_conv8(const __bf16* __restrict__ xb,
                                               const float* __restrict__ cwt,
                                               const float* __restrict__ cbv,
                                               __bf16* __restrict__ xo) {
  size_t idx = (size_t)blockIdx.x * 256 + threadIdx.x;   // < M*DI/8
  int dg = (int)(idx % (DI / 8));
  size_t row = idx / (DI / 8);
  int d0 = dg * 8;
  int t = (int)(row % Lc);
  size_t b = row / Lc;
  float acc[8];
  float4 cwv[8];
#pragma unroll
  for (int j = 0; j < 8; j++) {
    acc[j] = cbv[d0 + j];
    cwv[j] = *(const float4*)(cwt + (d0 + j) * DC);
  }
#pragma unroll
  for (int tap = 0; tap < DC; tap++) {
    int tt = t - (DC - 1) + tap;
    if (tt >= 0) {
      bf16x8 v = *(const bf16x8*)(xb + ((size_t)b * Lc + tt) * DI + d0);
#pragma unroll
      for (int j = 0; j < 8; j++) {
        float wt = (tap == 0) ? cwv[j].x : (tap == 1) ? cwv[j].y
                   : (tap == 2) ? cwv[j].z : cwv[j].w;
        acc[j] += wt * (float)v[j];
      }
    }
  }
  bf16x8 o;
#pragma unroll
  for (int j = 0; j < 8; j++) o[j] = (__bf16)siluf(acc[j]);
  *(bf16x8*)(xo + idx * 8) = o;
}

// ------ bf16 MFMA GEMM: 128x256 tile, BK=32, 512 threads, 2-phase LDS dbuf ------
// C[M x N] (+)= act(A[M x K(lda)] * W[N x K(ldw)]^T + bias)
// 8 waves (2M x 4N), per-wave 64x64. LDS 2x24KB = 48KB -> 3 blocks/CU.
// Session-converged optimum: 2-phase stage-ahead (R14), merged split epilogue
// (R17), bf16 residual RMW (R19), 128x256 geometry (R20), sub-chunked L2-aware
// XCD remap (R23/R24). Deeper pipelines / larger tiles all traded away
// resident-wave latency hiding and regressed (R8/R10/R11/R18/R21).
__global__ __launch_bounds__(512) void k_gemm_mfma(
    const __bf16* __restrict__ A, int lda,
    const __bf16* __restrict__ W, int ldw,
    const float* __restrict__ bias,
    float* __restrict__ Cf, __bf16* __restrict__ Cb, int ldc,
    int N, int K, int act, int resAdd,
    __bf16* __restrict__ Cb2, int Nsplit) {
  constexpr int BUFE = 12288;           // A 4096 + B 8192 elements per buffer
  __shared__ __bf16 lds[2 * BUFE];      // 48 KB
  int tid = threadIdx.x;
  int l = tid & 63, w = tid >> 6;       // 8 waves
  int wr = w >> 2, wc = w & 3;          // 2 M-halves x 4 N-quarters

  // L2-aware sub-chunked remap: XCD (lin&7) owns bm-blocks [xcd*cm, xcd*cm+cm);
  // within it, iterate all bn for 4 bm-blocks at a time (A sub-panel 1.18MB).
  int gm = gridDim.x;                   // # of 128-row bm blocks
  int nb = gridDim.y;                   // # of 256-col bn blocks
  int lin = blockIdx.y * gm + blockIdx.x;
  int cm = gm >> 3;                     // bm-blocks per XCD chunk (16)
  int xcd = lin & 7;
  int r = lin >> 3;                     // [0, cm*nb)
  int subi = r / (nb << 2);             // sub-chunk index (cm/4 of them)
  int rem  = r % (nb << 2);
  int bni  = rem >> 2;
  int bmj  = rem & 3;
  int bm = (xcd * cm + subi * 4 + bmj) << 7;
  int bn = bni << 8;                    // 256-wide N tiles

  // --- staging: A 512 chunks (1/thread), B 1024 chunks (2/thread); 16B each.
  int ra0 = 16 * w + (l >> 2);
  int rb0 = ra0;
  int rb1 = 128 + ra0;
  int sa0 = ((l & 3) - ra0 - (ra0 >> 2)) & 3;   // pre-permuted global k-slot
  int sb0 = sa0;
  int sb1 = ((l & 3) - rb1 - (rb1 >> 2)) & 3;
  const char* gA0 = (const char*)(A + (size_t)(bm + ra0) * lda) + sa0 * 16;
  const char* gB0 = (const char*)(W + (size_t)(bn + rb0) * ldw) + sb0 * 16;
  const char* gB1 = (const char*)(W + (size_t)(bn + rb1) * ldw) + sb1 * 16;
  int lA0 = (16 * w) * 32;                      // element offsets inside a buffer
  int lB0 = 4096 + (16 * w) * 32;
  int lB1 = 4096 + (128 + 16 * w) * 32;

  int aoff[4], boff[4];
#pragma unroll
  for (int i = 0; i < 4; i++) {
    int ra = wr * 64 + i * 16 + (l & 15);
    aoff[i] = ra * 32 + ((((l >> 4) + ra + (ra >> 2)) & 3) << 3);
    int rb = wc * 64 + i * 16 + (l & 15);
    boff[i] = 4096 + rb * 32 + ((((l >> 4) + rb + (rb >> 2)) & 3) << 3);
  }

  f32x4 acc[4][4];
#pragma unroll
  for (int i = 0; i < 4; i++)
#pragma unroll
    for (int j = 0; j < 4; j++)
#pragma unroll
      for (int e = 0; e < 4; e++) acc[i][j][e] = 0.f;

#define STAGE(t)                                                               \
  do {                                                                         \
    __bf16* Lb_ = lds + ((t) & 1) * BUFE;                                      \
    size_t kb_ = (size_t)(t) * 64;                                             \
    GLOAD16(gA0 + kb_, Lb_ + lA0);                                             \
    GLOAD16(gB0 + kb_, Lb_ + lB0);                                             \
    GLOAD16(gB1 + kb_, Lb_ + lB1);                                             \
  } while (0)

  int NT = K >> 5;
  STAGE(0);
  __syncthreads();                      // drain tile 0

  for (int t = 0; t < NT; ++t) {
    if (t + 1 < NT) STAGE(t + 1);       // async: in flight during compute of tile t
    const __bf16* Lb = lds + (t & 1) * BUFE;
    bf16x8 af[4], bfr[4];
#pragma unroll
    for (int i = 0; i < 4; i++) {
      af[i]  = *(const bf16x8*)(Lb + aoff[i]);
      bfr[i] = *(const bf16x8*)(Lb + boff[i]);
    }
    __builtin_amdgcn_s_setprio(1);
#pragma unroll
    for (int i = 0; i < 4; i++)
#pragma unroll
      for (int j = 0; j < 4; j++)
        acc[i][j] = __builtin_amdgcn_mfma_f32_16x16x32_bf16(af[i], bfr[j], acc[i][j], 0, 0, 0);
    __builtin_amdgcn_s_setprio(0);
    __syncthreads();                    // drains stage(t+1) + barrier (one per tile)
  }
#undef STAGE

#pragma unroll
  for (int i = 0; i < 4; i++) {
#pragma unroll
    for (int r2 = 0; r2 < 4; r2++) {
      int grow = bm + wr * 64 + i * 16 + (l >> 4) * 4 + r2;
#pragma unroll
      for (int j = 0; j < 4; j++) {
        int gcol = bn + wc * 64 + j * 16 + (l & 15);
        if (gcol < N) {
          float v = acc[i][j][r2];
          if (bias) v += bias[gcol];
          if (act == 1) v = softplusf(v);
          size_t off = (size_t)grow * ldc + gcol;
          if (Cb2) {
            if (gcol < Nsplit) Cb[off] = (__bf16)v;
            else               Cb2[(size_t)grow * ldc + (gcol - Nsplit)] = (__bf16)v;
          } else if (Cb) {
            if (resAdd) Cb[off] = (__bf16)((float)Cb[off] + v);
            else        Cb[off] = (__bf16)v;
          } else if (resAdd) {
            Cf[off] += v;
          } else {
            Cf[off] = v;
          }
        }
      }
    }
  }
}

// ---------------- chunked selective scan ----------------
// sc is bf16: [h0..h15 | P0..P15] per (b,c,d).  A_log fast path: Av[n] = -(n+1)
// (detected per-thread, exact fallback otherwise).
__global__ __launch_bounds__(256) void k_scan1(
    const __bf16* __restrict__ dlt,
    const __bf16* __restrict__ u_xc,
    const __bf16* __restrict__ xdbl,
    const float* __restrict__ alog,
    __bf16* __restrict__ sc) {
  __shared__ float bcs[CT][32];
  int b = blockIdx.z, c = blockIdx.y;
  int d = blockIdx.x * 256 + threadIdx.x;
  int row0 = b * Lc + c * CT;
#pragma unroll
  for (int k = 0; k < (CT * 32) / 256; k++) {
    int i = k * 256 + threadIdx.x;
    int t = i >> 5, j = i & 31;
    bcs[t][j] = (float)xdbl[(size_t)(row0 + t) * 80 + 48 + j];
  }
  float Av[16];
#pragma unroll
  for (int n = 0; n < 16; n++) Av[n] = -__expf(alog[d * DS + n]);
  bool fast = true;
#pragma unroll
  for (int n = 0; n < 16; n++) fast = fast && (fabsf(Av[n] + (float)(n + 1)) < 1e-4f);
  float h[16], P[16];
#pragma unroll
  for (int n = 0; n < 16; n++) { h[n] = 0.f; P[n] = 1.f; }
  float S = 0.f;
  __syncthreads();
  if (fast) {
    for (int t = 0; t < CT; t++) {
      size_t row = row0 + t;
      float dl = (float)dlt[row * DI + d];
      float u  = (float)u_xc[row * DI + d];
      float du = dl * u;
      float e[16];
      e[0] = __expf(-dl);
#pragma unroll
      for (int n = 1; n < 16; n++) e[n] = e[n - 1] * e[0];
#pragma unroll
      for (int n = 0; n < 16; n++) h[n] = h[n] * e[n] + du * bcs[t][n];
      S += dl;
    }
    P[0] = __expf(-S);
#pragma unroll
    for (int n = 1; n < 16; n++) P[n] = P[n - 1] * P[0];
  } else {
    for (int t = 0; t < CT; t++) {
      size_t row = row0 + t;
      float dl = (float)dlt[row * DI + d];
      float u  = (float)u_xc[row * DI + d];
      float du = dl * u;
#pragma unroll
      for (int n = 0; n < 16; n++) {
        float e = __expf(dl * Av[n]);
        h[n] = h[n] * e + du * bcs[t][n];
        P[n] *= e;
      }
    }
  }
  __bf16* o = sc + (((size_t)b * NC + c) * DI + d) * 32;
  bf16x8 v0, v1, v2, v3;
#pragma unroll
  for (int n = 0; n < 8; n++) { v0[n] = (__bf16)h[n]; v1[n] = (__bf16)h[8 + n];
                                v2[n] = (__bf16)P[n]; v3[n] = (__bf16)P[8 + n]; }
  *(bf16x8*)(o)      = v0;
  *(bf16x8*)(o + 8)  = v1;
  *(bf16x8*)(o + 16) = v2;
  *(bf16x8*)(o + 24) = v3;
}

__global__ __launch_bounds__(256) void k_scan2(__bf16* __restrict__ sc) {
  int g = blockIdx.x * 256 + threadIdx.x;
  int n = g & 15;
  int rest = g >> 4;
  int d = rest % DI;
  int b = rest / DI;
  float cur = 0.f;
  for (int c = 0; c < NC; c++) {
    __bf16* p = sc + (((size_t)b * NC + c) * DI + d) * 32;
    float hf = (float)p[n];
    float pd = (float)p[16 + n];
    p[n] = (__bf16)cur;
    cur = pd * cur + hf;
  }
}

__global__ __launch_bounds__(256) void k_scan3(
    const __bf16* __restrict__ dlt,
    const __bf16* __restrict__ zb,
    __bf16* __restrict__ u_xc,          // in: u, out: y*silu(z)
    const __bf16* __restrict__ xdbl,
    const float* __restrict__ alog,
    const float* __restrict__ dsk,
    const __bf16* __restrict__ sc) {
  __shared__ float bcs[CT][32];
  int b = blockIdx.z, c = blockIdx.y;
  int d = blockIdx.x * 256 + threadIdx.x;
  int row0 = b * Lc + c * CT;
#pragma unroll
  for (int k = 0; k < (CT * 32) / 256; k++) {
    int i = k * 256 + threadIdx.x;
    int t = i >> 5, j = i & 31;
    bcs[t][j] = (float)xdbl[(size_t)(row0 + t) * 80 + 48 + j];
  }
  float Av[16];
#pragma unroll
  for (int n = 0; n < 16; n++) Av[n] = -__expf(alog[d * DS + n]);
  bool fast = true;
#pragma unroll
  for (int n = 0; n < 16; n++) fast = fast && (fabsf(Av[n] + (float)(n + 1)) < 1e-4f);
  float Dv = dsk[d];
  float h[16];
  const __bf16* ip = sc + (((size_t)b * NC + c) * DI + d) * 32;
  {
    bf16x8 v0 = *(const bf16x8*)(ip);
    bf16x8 v1 = *(const bf16x8*)(ip + 8);
#pragma unroll
    for (int n = 0; n < 8; n++) { h[n] = (float)v0[n]; h[8 + n] = (float)v1[n]; }
  }
  __syncthreads();
  if (fast) {
    for (int t = 0; t < CT; t++) {
      size_t row = row0 + t;
      float dl = (float)dlt[row * DI + d];
      float u  = (float)u_xc[row * DI + d];
      float du = dl * u;
      float e[16];
      e[0] = __expf(-dl);
#pragma unroll
      for (int n = 1; n < 16; n++) e[n] = e[n - 1] * e[0];
      float y = 0.f;
#pragma unroll
      for (int n = 0; n < 16; n++) {
        h[n] = h[n] * e[n] + du * bcs[t][n];
        y += h[n] * bcs[t][16 + n];
      }
      y += u * Dv;
      float z = (float)zb[row * DI + d];
      u_xc[row * DI + d] = (__bf16)(y * siluf(z));
    }
  } else {
    for (int t = 0; t < CT; t++) {
      size_t row = row0 + t;
      float dl = (float)dlt[row * DI + d];
      float u  = (float)u_xc[row * DI + d];
      float du = dl * u;
      float y = 0.f;
#pragma unroll
      for (int n = 0; n < 16; n++) {
        float e = __expf(dl * Av[n]);
        h[n] = h[n] * e + du * bcs[t][n];
        y += h[n] * bcs[t][16 + n];
      }
      y += u * Dv;
      float z = (float)zb[row * DI + d];
      u_xc[row * DI + d] = (__bf16)(y * siluf(z));
    }
  }
}

}  // namespace

extern "C" void kernel_launch(void* const* d_in, const int* in_sizes, int n_in,
                              void* d_out, int out_size, void* d_ws, size_t ws_size,
                              hipStream_t stream) {
  const int*   ids   = (const int*)d_in[0];
  const float* times = (const float*)d_in[1];
  const float* emb   = (const float*)d_in[3];
  const float* tw    = (const float*)d_in[4];
  const float* tb    = (const float*)d_in[5];
  const float* inw   = (const float*)d_in[6];
  const float* cw    = (const float*)d_in[7];
  const float* cb    = (const float*)d_in[8];
  const float* xw    = (const float*)d_in[9];
  const float* dtw   = (const float*)d_in[10];
  const float* dtb   = (const float*)d_in[11];
  const float* alog  = (const float*)d_in[12];
  const float* dsk   = (const float*)d_in[13];
  const float* ow    = (const float*)d_in[14];
  const float* nw    = (const float*)d_in[15];
  const float* nfw   = (const float*)d_in[16];
  float* out = (float*)d_out;

  // ---- workspace layout (bf16; 16B aligned) ----
  __bf16* wsb = (__bf16*)d_ws;
  __bf16* hb    = wsb;  wsb += (size_t)M * DM;               // 25.2 MB (bf16 residual)
  __bf16* hnb   = wsb;  wsb += (size_t)M * DM;               // 25.2 MB
  __bf16* xb    = wsb;  wsb += (size_t)M * DI;               // 50.3 MB
  __bf16* zbuf  = wsb;  wsb += (size_t)M * DI;               // 50.3 MB
  __bf16* xcb   = wsb;  wsb += (size_t)M * DI;               // 50.3 MB
  __bf16* dltb  = wsb;  wsb += (size_t)M * DI;               // 50.3 MB (bf16 delta)
  __bf16* scb   = wsb;  wsb += (size_t)Bc * NC * DI * 32;    // 25.2 MB (bf16 chunk states)
  __bf16* xdblb = wsb;  wsb += (size_t)M * 80;               // 2.6 MB
  __bf16* ebw   = wsb;  wsb += (size_t)VOCP * DM;            // 3.1 MB
  __bf16* inwb  = wsb;  wsb += (size_t)4 * 2 * DI * DM;      // 18.9 MB
  __bf16* xwb   = wsb;  wsb += (size_t)4 * 256 * DI;         // 3.1 MB (80->256 rows)
  __bf16* owb   = wsb;  wsb += (size_t)4 * DM * DI;          // 9.4 MB
  __bf16* dtwb  = wsb;  wsb += (size_t)4 * DI * 64;          // 0.8 MB

  // weight / embed conversions (every call; deterministic)
  k_f2b<<<2048, 256, 0, stream>>>(inw, inwb, (4 * 2 * DI * DM) / 4);
  k_f2b<<<2048, 256, 0, stream>>>(ow,  owb,  (4 * DM * DI) / 4);
  k_f2b_pad<<<2048, 256, 0, stream>>>(emb, ebw, 1, VOC, VOCP, DM, DM);
  k_f2b_pad<<<2048, 256, 0, stream>>>(xw,  xwb, 4, 80, 256, DI, DI);
  k_f2b_pad<<<1024, 256, 0, stream>>>(dtw, dtwb, 4, DI, DI, DR, 64);

  k_embed<<<M, 256, 0, stream>>>(ids, times, emb, tw, tb, hb);

  for (int i = 0; i < 4; i++) {
    k_rmsnorm<<<M, 256, 0, stream>>>(hb, nw + i * DM, hnb);
    {  // [x | z] = hn @ in_proj^T  (ONE dispatch, split bf16 outputs xb / zbuf)
      dim3 g(M / 128, (2 * DI) / 256);
      k_gemm_mfma<<<g, 512, 0, stream>>>(hnb, DM, inwb + (size_t)i * 2 * DI * DM, DM,
                                         nullptr, nullptr, xb, DI, 2 * DI, DM, 0, 0,
                                         zbuf, DI);
    }
    {  // xcb = silu(conv1d(x) + cb)   (vectorized, 8 d's per thread)
      int blocks = (int)(((size_t)M * DI / 8) / 256);
      k_conv8<<<blocks, 256, 0, stream>>>(xb, cw + i * DI * DC, cb + i * DI, xcb);
    }
    {  // xdbl = u @ x_proj^T  (bf16 out, N=80, weights padded to 256 rows)
      dim3 g(M / 128, 1);
      k_gemm_mfma<<<g, 512, 0, stream>>>(xcb, DI, xwb + (size_t)i * 256 * DI, DI,
                                         nullptr, nullptr, xdblb, 80, 80, DI, 0, 0,
                                         nullptr, 0);
    }
    {  // delta = softplus(xdbl @ dtw_pad^T + dtb)  -> bf16 (K=64)
      dim3 g(M / 128, DI / 256);
      k_gemm_mfma<<<g, 512, 0, stream>>>(xdblb, 80, dtwb + (size_t)i * DI * 64, 64,
                                         dtb + i * DI, nullptr, dltb, DI, DI, 64, 1, 0,
                                         nullptr, 0);
    }
    {  // chunked selective scan + y*silu(z), in place over xcb
      dim3 g1(DI / 256, NC, Bc);
      k_scan1<<<g1, 256, 0, stream>>>(dltb, xcb, xdblb, alog + (size_t)i * DI * DS, scb);
      k_scan2<<<(Bc * DI * DS) / 256, 256, 0, stream>>>(scb);
      k_scan3<<<g1, 256, 0, stream>>>(dltb, zbuf, xcb, xdblb,
                                      alog + (size_t)i * DI * DS, dsk + i * DI, scb);
    }
    {  // h += y @ out_proj^T   (bf16 RMW resAdd)
      dim3 g(M / 128, DM / 256);
      k_gemm_mfma<<<g, 512, 0, stream>>>(xcb, DI, owb + (size_t)i * DM * DI, DI,
                                         nullptr, nullptr, hb, DM, DM, DI, 0, 1,
                                         nullptr, 0);
    }
  }

  k_rmsnorm<<<M, 256, 0, stream>>>(hb, nfw, hnb);
  {  // logits = hn @ embed^T   (N=1969, padded rows, f32 out)
    dim3 g(M / 128, VOCP / 256);
    k_gemm_mfma<<<g, 512, 0, stream>>>(hnb, DM, ebw, DM,
                                       nullptr, out, nullptr, VOC, VOC, DM, 0, 0,
                                       nullptr, 0);
  }
}

// Round 28
// 2191.448 us; speedup vs baseline: 1.0368x; 1.0010x over previous
//
#include <hip/hip_runtime.h>
#include <hip/hip_bf16.h>
#include <math.h>

namespace {

constexpr int Bc  = 8;
constexpr int Lc  = 2048;
constexpr int VOC = 1969;
constexpr int VOCP = 2048;            // padded vocab rows for logits GEMM
constexpr int DM  = 768;
constexpr int DI  = 1536;
constexpr int DS  = 16;
constexpr int DC  = 4;
constexpr int DR  = 48;
constexpr int M   = Bc * Lc;          // 16384 rows
constexpr int NC  = 32;               // scan chunks (measured optimum; NC=16 regressed)
constexpr int CT  = Lc / NC;          // 64 timesteps per chunk
constexpr float EPS_ = 1e-5f;

typedef __bf16 bf16x8 __attribute__((ext_vector_type(8)));
typedef float  f32x4  __attribute__((ext_vector_type(4)));

__device__ __forceinline__ float siluf(float x) { return x / (1.f + __expf(-x)); }
__device__ __forceinline__ float softplusf(float x) {
  return (x > 20.f) ? x : __logf(1.f + __expf(x));
}

#define GLOAD16(gp, lp)                                                        \
  __builtin_amdgcn_global_load_lds(                                            \
      (const __attribute__((address_space(1))) void*)(gp),                     \
      (__attribute__((address_space(3))) void*)(lp), 16, 0, 0)

// -------- f32 -> bf16 conversion (packed) --------
__global__ __launch_bounds__(256) void k_f2b(const float* __restrict__ in,
                                             __bf16* __restrict__ out, int n4) {
  for (int i = blockIdx.x * 256 + threadIdx.x; i < n4; i += gridDim.x * 256) {
    float4 v = *(const float4*)(in + (size_t)i * 4);
    __bf16* o = out + (size_t)i * 4;
    o[0] = (__bf16)v.x; o[1] = (__bf16)v.y; o[2] = (__bf16)v.z; o[3] = (__bf16)v.w;
  }
}

// f32 -> bf16 with per-layer row/col zero-padding.
__global__ __launch_bounds__(256) void k_f2b_pad(const float* __restrict__ in,
                                                 __bf16* __restrict__ out,
                                                 int layers, int rin, int rout,
                                                 int cin, int cout) {
  size_t total = (size_t)layers * rout * cout;
  for (size_t i = (size_t)blockIdx.x * 256 + threadIdx.x; i < total;
       i += (size_t)gridDim.x * 256) {
    int lay = (int)(i / ((size_t)rout * cout));
    int rem = (int)(i % ((size_t)rout * cout));
    int r = rem / cout, c = rem % cout;
    float v = (r < rin && c < cin) ? in[((size_t)lay * rin + r) * cin + c] : 0.f;
    out[i] = (__bf16)v;
  }
}

// h[row,d] = embed[ids[row]][d] + times[row]*time_w[d] + time_b[d]   (bf16 h)
__global__ void k_embed(const int* __restrict__ ids, const float* __restrict__ times,
                        const float* __restrict__ emb, const float* __restrict__ tw,
                        const float* __restrict__ tb, __bf16* __restrict__ h) {
  int row = blockIdx.x;
  int id  = ids[row];
  float tv = times[row];
  const float* e = emb + (size_t)id * DM;
  for (int d = threadIdx.x; d < DM; d += blockDim.x)
    h[(size_t)row * DM + d] = (__bf16)(e[d] + tv * tw[d] + tb[d]);
}

// bf16 in/out: o[row,:] = h[row,:] * rsqrt(mean(h^2)+eps) * w
__global__ __launch_bounds__(256) void k_rmsnorm(const __bf16* __restrict__ x,
                                                 const float* __restrict__ w,
                                                 __bf16* __restrict__ o) {
  int row = blockIdx.x;
  const __bf16* xr = x + (size_t)row * DM;
  float v[3];
  float s = 0.f;
#pragma unroll
  for (int i = 0; i < 3; i++) { v[i] = (float)xr[threadIdx.x + 256 * i]; s += v[i] * v[i]; }
#pragma unroll
  for (int off = 32; off > 0; off >>= 1) s += __shfl_down(s, off);
  __shared__ float red[4];
  int lane = threadIdx.x & 63, wv = threadIdx.x >> 6;
  if (lane == 0) red[wv] = s;
  __syncthreads();
  if (threadIdx.x == 0)
    red[0] = rsqrtf((red[0] + red[1] + red[2] + red[3]) / (float)DM + EPS_);
  __syncthreads();
  float sc = red[0];
#pragma unroll
  for (int i = 0; i < 3; i++) {
    int d = threadIdx.x + 256 * i;
    o[(size_t)row * DM + d] = (__bf16)(v[i] * sc * w[d]);
  }
}

// Depthwise causal conv (width 4) + bias + silu ; bf16x8 vectorized, dense [M][DI].
__global__ __launch_bounds__(256) void k_conv8(const __bf16* __restrict__ xb,
                                               const float* __restrict__ cwt,
                                               const float* __restrict__ cbv,
                                               __bf16* __restrict__ xo) {
  size_t idx = (size_t)blockIdx.x * 256 + threadIdx.x;   // < M*DI/8
  int dg = (int)(idx % (DI / 8));
  size_t row = idx / (DI / 8);
  int d0 = dg * 8;
  int t = (int)(row % Lc);
  size_t b = row / Lc;
  float acc[8];
  float4 cwv[8];
#pragma unroll
  for (int j = 0; j < 8; j++) {
    acc[j] = cbv[d0 + j];
    cwv[j] = *(const float4*)(cwt + (d0 + j) * DC);
  }
#pragma unroll
  for (int tap = 0; tap < DC; tap++) {
    int tt = t - (DC - 1) + tap;
    if (tt >= 0) {
      bf16x8 v = *(const bf16x8*)(xb + ((size_t)b * Lc + tt) * DI + d0);
#pragma unroll
      for (int j = 0; j < 8; j++) {
        float wt = (tap == 0) ? cwv[j].x : (tap == 1) ? cwv[j].y
                   : (tap == 2) ? cwv[j].z : cwv[j].w;
        acc[j] += wt * (float)v[j];
      }
    }
  }
  bf16x8 o;
#pragma unroll
  for (int j = 0; j < 8; j++) o[j] = (__bf16)siluf(acc[j]);
  *(bf16x8*)(xo + idx * 8) = o;
}

// ------ bf16 MFMA GEMM: 128x256 tile, BK=32, 512 threads, 2-phase LDS dbuf ------
// Session-converged optimum (see R24 notes); unchanged this round.
__global__ __launch_bounds__(512) void k_gemm_mfma(
    const __bf16* __restrict__ A, int lda,
    const __bf16* __restrict__ W, int ldw,
    const float* __restrict__ bias,
    float* __restrict__ Cf, __bf16* __restrict__ Cb, int ldc,
    int N, int K, int act, int resAdd,
    __bf16* __restrict__ Cb2, int Nsplit) {
  constexpr int BUFE = 12288;           // A 4096 + B 8192 elements per buffer
  __shared__ __bf16 lds[2 * BUFE];      // 48 KB
  int tid = threadIdx.x;
  int l = tid & 63, w = tid >> 6;       // 8 waves
  int wr = w >> 2, wc = w & 3;          // 2 M-halves x 4 N-quarters

  // L2-aware sub-chunked remap: XCD (lin&7) owns bm-blocks [xcd*cm, xcd*cm+cm);
  // within it, iterate all bn for 4 bm-blocks at a time (A sub-panel 1.18MB).
  int gm = gridDim.x;                   // # of 128-row bm blocks
  int nb = gridDim.y;                   // # of 256-col bn blocks
  int lin = blockIdx.y * gm + blockIdx.x;
  int cm = gm >> 3;                     // bm-blocks per XCD chunk (16)
  int xcd = lin & 7;
  int r = lin >> 3;                     // [0, cm*nb)
  int subi = r / (nb << 2);             // sub-chunk index (cm/4 of them)
  int rem  = r % (nb << 2);
  int bni  = rem >> 2;
  int bmj  = rem & 3;
  int bm = (xcd * cm + subi * 4 + bmj) << 7;
  int bn = bni << 8;                    // 256-wide N tiles

  // --- staging: A 512 chunks (1/thread), B 1024 chunks (2/thread); 16B each.
  int ra0 = 16 * w + (l >> 2);
  int rb0 = ra0;
  int rb1 = 128 + ra0;
  int sa0 = ((l & 3) - ra0 - (ra0 >> 2)) & 3;   // pre-permuted global k-slot
  int sb0 = sa0;
  int sb1 = ((l & 3) - rb1 - (rb1 >> 2)) & 3;
  const char* gA0 = (const char*)(A + (size_t)(bm + ra0) * lda) + sa0 * 16;
  const char* gB0 = (const char*)(W + (size_t)(bn + rb0) * ldw) + sb0 * 16;
  const char* gB1 = (const char*)(W + (size_t)(bn + rb1) * ldw) + sb1 * 16;
  int lA0 = (16 * w) * 32;                      // element offsets inside a buffer
  int lB0 = 4096 + (16 * w) * 32;
  int lB1 = 4096 + (128 + 16 * w) * 32;

  int aoff[4], boff[4];
#pragma unroll
  for (int i = 0; i < 4; i++) {
    int ra = wr * 64 + i * 16 + (l & 15);
    aoff[i] = ra * 32 + ((((l >> 4) + ra + (ra >> 2)) & 3) << 3);
    int rb = wc * 64 + i * 16 + (l & 15);
    boff[i] = 4096 + rb * 32 + ((((l >> 4) + rb + (rb >> 2)) & 3) << 3);
  }

  f32x4 acc[4][4];
#pragma unroll
  for (int i = 0; i < 4; i++)
#pragma unroll
    for (int j = 0; j < 4; j++)
#pragma unroll
      for (int e = 0; e < 4; e++) acc[i][j][e] = 0.f;

#define STAGE(t)                                                               \
  do {                                                                         \
    __bf16* Lb_ = lds + ((t) & 1) * BUFE;                                      \
    size_t kb_ = (size_t)(t) * 64;                                             \
    GLOAD16(gA0 + kb_, Lb_ + lA0);                                             \
    GLOAD16(gB0 + kb_, Lb_ + lB0);                                             \
    GLOAD16(gB1 + kb_, Lb_ + lB1);                                             \
  } while (0)

  int NT = K >> 5;
  STAGE(0);
  __syncthreads();                      // drain tile 0

  for (int t = 0; t < NT; ++t) {
    if (t + 1 < NT) STAGE(t + 1);       // async: in flight during compute of tile t
    const __bf16* Lb = lds + (t & 1) * BUFE;
    bf16x8 af[4], bfr[4];
#pragma unroll
    for (int i = 0; i < 4; i++) {
      af[i]  = *(const bf16x8*)(Lb + aoff[i]);
      bfr[i] = *(const bf16x8*)(Lb + boff[i]);
    }
    __builtin_amdgcn_s_setprio(1);
#pragma unroll
    for (int i = 0; i < 4; i++)
#pragma unroll
      for (int j = 0; j < 4; j++)
        acc[i][j] = __builtin_amdgcn_mfma_f32_16x16x32_bf16(af[i], bfr[j], acc[i][j], 0, 0, 0);
    __builtin_amdgcn_s_setprio(0);
    __syncthreads();                    // drains stage(t+1) + barrier (one per tile)
  }
#undef STAGE

#pragma unroll
  for (int i = 0; i < 4; i++) {
#pragma unroll
    for (int r2 = 0; r2 < 4; r2++) {
      int grow = bm + wr * 64 + i * 16 + (l >> 4) * 4 + r2;
#pragma unroll
      for (int j = 0; j < 4; j++) {
        int gcol = bn + wc * 64 + j * 16 + (l & 15);
        if (gcol < N) {
          float v = acc[i][j][r2];
          if (bias) v += bias[gcol];
          if (act == 1) v = softplusf(v);
          size_t off = (size_t)grow * ldc + gcol;
          if (Cb2) {
            if (gcol < Nsplit) Cb[off] = (__bf16)v;
            else               Cb2[(size_t)grow * ldc + (gcol - Nsplit)] = (__bf16)v;
          } else if (Cb) {
            if (resAdd) Cb[off] = (__bf16)((float)Cb[off] + v);
            else        Cb[off] = (__bf16)v;
          } else if (resAdd) {
            Cf[off] += v;
          } else {
            Cf[off] = v;
          }
        }
      }
    }
  }
}

// ---------------- chunked selective scan ----------------
// sc is bf16: [h0..h15 | P0..P15] per (b,c,d).  A_log fast path: Av[n] = -(n+1)
// (detected per-thread, exact fallback otherwise).
__global__ __launch_bounds__(256) void k_scan1(
    const __bf16* __restrict__ dlt,
    const __bf16* __restrict__ u_xc,
    const __bf16* __restrict__ xdbl,
    const float* __restrict__ alog,
    __bf16* __restrict__ sc) {
  __shared__ float bcs[CT][32];
  int b = blockIdx.z, c = blockIdx.y;
  int d = blockIdx.x * 256 + threadIdx.x;
  int row0 = b * Lc + c * CT;
#pragma unroll
  for (int k = 0; k < (CT * 32) / 256; k++) {
    int i = k * 256 + threadIdx.x;
    int t = i >> 5, j = i & 31;
    bcs[t][j] = (float)xdbl[(size_t)(row0 + t) * 80 + 48 + j];
  }
  float Av[16];
#pragma unroll
  for (int n = 0; n < 16; n++) Av[n] = -__expf(alog[d * DS + n]);
  bool fast = true;
#pragma unroll
  for (int n = 0; n < 16; n++) fast = fast && (fabsf(Av[n] + (float)(n + 1)) < 1e-4f);
  float h[16], P[16];
#pragma unroll
  for (int n = 0; n < 16; n++) { h[n] = 0.f; P[n] = 1.f; }
  float S = 0.f;
  __syncthreads();
  if (fast) {
    for (int t = 0; t < CT; t++) {
      size_t row = row0 + t;
      float dl = (float)dlt[row * DI + d];
      float u  = (float)u_xc[row * DI + d];
      float du = dl * u;
      float e[16];
      e[0] = __expf(-dl);
#pragma unroll
      for (int n = 1; n < 16; n++) e[n] = e[n - 1] * e[0];
#pragma unroll
      for (int n = 0; n < 16; n++) h[n] = h[n] * e[n] + du * bcs[t][n];
      S += dl;
    }
    P[0] = __expf(-S);
#pragma unroll
    for (int n = 1; n < 16; n++) P[n] = P[n - 1] * P[0];
  } else {
    for (int t = 0; t < CT; t++) {
      size_t row = row0 + t;
      float dl = (float)dlt[row * DI + d];
      float u  = (float)u_xc[row * DI + d];
      float du = dl * u;
#pragma unroll
      for (int n = 0; n < 16; n++) {
        float e = __expf(dl * Av[n]);
        h[n] = h[n] * e + du * bcs[t][n];
        P[n] *= e;
      }
    }
  }
  __bf16* o = sc + (((size_t)b * NC + c) * DI + d) * 32;
  bf16x8 v0, v1, v2, v3;
#pragma unroll
  for (int n = 0; n < 8; n++) { v0[n] = (__bf16)h[n]; v1[n] = (__bf16)h[8 + n];
                                v2[n] = (__bf16)P[n]; v3[n] = (__bf16)P[8 + n]; }
  *(bf16x8*)(o)      = v0;
  *(bf16x8*)(o + 8)  = v1;
  *(bf16x8*)(o + 16) = v2;
  *(bf16x8*)(o + 24) = v3;
}

// Pass 2 v2: batch the 32 chunk loads up front (independent -> one latency
// exposure), run the 32-step recurrence in registers, then write back h_in.
// Replaces 32 dependent global round-trips with ~2 latency exposures.
// All array indices compile-time constant (fully unrolled) -> registers.
__global__ __launch_bounds__(256) void k_scan2(__bf16* __restrict__ sc) {
  int g = blockIdx.x * 256 + threadIdx.x;
  int n = g & 15;
  int rest = g >> 4;
  int d = rest % DI;
  int b = rest / DI;
  __bf16* base = sc + ((size_t)b * NC * DI + d) * 32;
  constexpr size_t CSTRIDE = (size_t)DI * 32;   // elements between chunks
  float hf[NC], pd[NC];
#pragma unroll
  for (int c = 0; c < NC; c++) {
    const __bf16* p = base + c * CSTRIDE;
    hf[c] = (float)p[n];
    pd[c] = (float)p[16 + n];
  }
  float cur = 0.f;
#pragma unroll
  for (int c = 0; c < NC; c++) {
    base[c * CSTRIDE + n] = (__bf16)cur;
    cur = pd[c] * cur + hf[c];
  }
}

__global__ __launch_bounds__(256) void k_scan3(
    const __bf16* __restrict__ dlt,
    const __bf16* __restrict__ zb,
    __bf16* __restrict__ u_xc,          // in: u, out: y*silu(z)
    const __bf16* __restrict__ xdbl,
    const float* __restrict__ alog,
    const float* __restrict__ dsk,
    const __bf16* __restrict__ sc) {
  __shared__ float bcs[CT][32];
  int b = blockIdx.z, c = blockIdx.y;
  int d = blockIdx.x * 256 + threadIdx.x;
  int row0 = b * Lc + c * CT;
#pragma unroll
  for (int k = 0; k < (CT * 32) / 256; k++) {
    int i = k * 256 + threadIdx.x;
    int t = i >> 5, j = i & 31;
    bcs[t][j] = (float)xdbl[(size_t)(row0 + t) * 80 + 48 + j];
  }
  float Av[16];
#pragma unroll
  for (int n = 0; n < 16; n++) Av[n] = -__expf(alog[d * DS + n]);
  bool fast = true;
#pragma unroll
  for (int n = 0; n < 16; n++) fast = fast && (fabsf(Av[n] + (float)(n + 1)) < 1e-4f);
  float Dv = dsk[d];
  float h[16];
  const __bf16* ip = sc + (((size_t)b * NC + c) * DI + d) * 32;
  {
    bf16x8 v0 = *(const bf16x8*)(ip);
    bf16x8 v1 = *(const bf16x8*)(ip + 8);
#pragma unroll
    for (int n = 0; n < 8; n++) { h[n] = (float)v0[n]; h[8 + n] = (float)v1[n]; }
  }
  __syncthreads();
  if (fast) {
    for (int t = 0; t < CT; t++) {
      size_t row = row0 + t;
      float dl = (float)dlt[row * DI + d];
      float u  = (float)u_xc[row * DI + d];
      float du = dl * u;
      float e[16];
      e[0] = __expf(-dl);
#pragma unroll
      for (int n = 1; n < 16; n++) e[n] = e[n - 1] * e[0];
      float y = 0.f;
#pragma unroll
      for (int n = 0; n < 16; n++) {
        h[n] = h[n] * e[n] + du * bcs[t][n];
        y += h[n] * bcs[t][16 + n];
      }
      y += u * Dv;
      float z = (float)zb[row * DI + d];
      u_xc[row * DI + d] = (__bf16)(y * siluf(z));
    }
  } else {
    for (int t = 0; t < CT; t++) {
      size_t row = row0 + t;
      float dl = (float)dlt[row * DI + d];
      float u  = (float)u_xc[row * DI + d];
      float du = dl * u;
      float y = 0.f;
#pragma unroll
      for (int n = 0; n < 16; n++) {
        float e = __expf(dl * Av[n]);
        h[n] = h[n] * e + du * bcs[t][n];
        y += h[n] * bcs[t][16 + n];
      }
      y += u * Dv;
      float z = (float)zb[row * DI + d];
      u_xc[row * DI + d] = (__bf16)(y * siluf(z));
    }
  }
}

}  // namespace

extern "C" void kernel_launch(void* const* d_in, const int* in_sizes, int n_in,
                              void* d_out, int out_size, void* d_ws, size_t ws_size,
                              hipStream_t stream) {
  const int*   ids   = (const int*)d_in[0];
  const float* times = (const float*)d_in[1];
  const float* emb   = (const float*)d_in[3];
  const float* tw    = (const float*)d_in[4];
  const float* tb    = (const float*)d_in[5];
  const float* inw   = (const float*)d_in[6];
  const float* cw    = (const float*)d_in[7];
  const float* cb    = (const float*)d_in[8];
  const float* xw    = (const float*)d_in[9];
  const float* dtw   = (const float*)d_in[10];
  const float* dtb   = (const float*)d_in[11];
  const float* alog  = (const float*)d_in[12];
  const float* dsk   = (const float*)d_in[13];
  const float* ow    = (const float*)d_in[14];
  const float* nw    = (const float*)d_in[15];
  const float* nfw   = (const float*)d_in[16];
  float* out = (float*)d_out;

  // ---- workspace layout (bf16; 16B aligned) ----
  __bf16* wsb = (__bf16*)d_ws;
  __bf16* hb    = wsb;  wsb += (size_t)M * DM;               // 25.2 MB (bf16 residual)
  __bf16* hnb   = wsb;  wsb += (size_t)M * DM;               // 25.2 MB
  __bf16* xb    = wsb;  wsb += (size_t)M * DI;               // 50.3 MB
  __bf16* zbuf  = wsb;  wsb += (size_t)M * DI;               // 50.3 MB
  __bf16* xcb   = wsb;  wsb += (size_t)M * DI;               // 50.3 MB
  __bf16* dltb  = wsb;  wsb += (size_t)M * DI;               // 50.3 MB (bf16 delta)
  __bf16* scb   = wsb;  wsb += (size_t)Bc * NC * DI * 32;    // 25.2 MB (bf16 chunk states)
  __bf16* xdblb = wsb;  wsb += (size_t)M * 80;               // 2.6 MB
  __bf16* ebw   = wsb;  wsb += (size_t)VOCP * DM;            // 3.1 MB
  __bf16* inwb  = wsb;  wsb += (size_t)4 * 2 * DI * DM;      // 18.9 MB
  __bf16* xwb   = wsb;  wsb += (size_t)4 * 256 * DI;         // 3.1 MB (80->256 rows)
  __bf16* owb   = wsb;  wsb += (size_t)4 * DM * DI;          // 9.4 MB
  __bf16* dtwb  = wsb;  wsb += (size_t)4 * DI * 64;          // 0.8 MB

  // weight / embed conversions (every call; deterministic)
  k_f2b<<<2048, 256, 0, stream>>>(inw, inwb, (4 * 2 * DI * DM) / 4);
  k_f2b<<<2048, 256, 0, stream>>>(ow,  owb,  (4 * DM * DI) / 4);
  k_f2b_pad<<<2048, 256, 0, stream>>>(emb, ebw, 1, VOC, VOCP, DM, DM);
  k_f2b_pad<<<2048, 256, 0, stream>>>(xw,  xwb, 4, 80, 256, DI, DI);
  k_f2b_pad<<<1024, 256, 0, stream>>>(dtw, dtwb, 4, DI, DI, DR, 64);

  k_embed<<<M, 256, 0, stream>>>(ids, times, emb, tw, tb, hb);

  for (int i = 0; i < 4; i++) {
    k_rmsnorm<<<M, 256, 0, stream>>>(hb, nw + i * DM, hnb);
    {  // [x | z] = hn @ in_proj^T  (ONE dispatch, split bf16 outputs xb / zbuf)
      dim3 g(M / 128, (2 * DI) / 256);
      k_gemm_mfma<<<g, 512, 0, stream>>>(hnb, DM, inwb + (size_t)i * 2 * DI * DM, DM,
                                         nullptr, nullptr, xb, DI, 2 * DI, DM, 0, 0,
                                         zbuf, DI);
    }
    {  // xcb = silu(conv1d(x) + cb)   (vectorized, 8 d's per thread)
      int blocks = (int)(((size_t)M * DI / 8) / 256);
      k_conv8<<<blocks, 256, 0, stream>>>(xb, cw + i * DI * DC, cb + i * DI, xcb);
    }
    {  // xdbl = u @ x_proj^T  (bf16 out, N=80, weights padded to 256 rows)
      dim3 g(M / 128, 1);
      k_gemm_mfma<<<g, 512, 0, stream>>>(xcb, DI, xwb + (size_t)i * 256 * DI, DI,
                                         nullptr, nullptr, xdblb, 80, 80, DI, 0, 0,
                                         nullptr, 0);
    }
    {  // delta = softplus(xdbl @ dtw_pad^T + dtb)  -> bf16 (K=64)
      dim3 g(M / 128, DI / 256);
      k_gemm_mfma<<<g, 512, 0, stream>>>(xdblb, 80, dtwb + (size_t)i * DI * 64, 64,
                                         dtb + i * DI, nullptr, dltb, DI, DI, 64, 1, 0,
                                         nullptr, 0);
    }
    {  // chunked selective scan + y*silu(z), in place over xcb
      dim3 g1(DI / 256, NC, Bc);
      k_scan1<<<g1, 256, 0, stream>>>(dltb, xcb, xdblb, alog + (size_t)i * DI * DS, scb);
      k_scan2<<<(Bc * DI * DS) / 256, 256, 0, stream>>>(scb);
      k_scan3<<<g1, 256, 0, stream>>>(dltb, zbuf, xcb, xdblb,
                                      alog + (size_t)i * DI * DS, dsk + i * DI, scb);
    }
    {  // h += y @ out_proj^T   (bf16 RMW resAdd)
      dim3 g(M / 128, DM / 256);
      k_gemm_mfma<<<g, 512, 0, stream>>>(xcb, DI, owb + (size_t)i * DM * DI, DI,
                                         nullptr, nullptr, hb, DM, DM, DI, 0, 1,
                                         nullptr, 0);
    }
  }

  k_rmsnorm<<<M, 256, 0, stream>>>(hb, nfw, hnb);
  {  // logits = hn @ embed^T   (N=1969, padded rows, f32 out)
    dim3 g(M / 128, VOCP / 256);
    k_gemm_mfma<<<g, 512, 0, stream>>>(hnb, DM, ebw, DM,
                                       nullptr, out, nullptr, VOC, VOC, DM, 0, 0,
                                       nullptr, 0);
  }
}

// Round 29
// 2185.581 us; speedup vs baseline: 1.0396x; 1.0027x over previous
//
#include <hip/hip_runtime.h>
#include <hip/hip_bf16.h>
#include <math.h>

namespace {

constexpr int Bc  = 8;
constexpr int Lc  = 2048;
constexpr int VOC = 1969;
constexpr int VOCP = 2048;            // padded vocab rows for logits GEMM
constexpr int DM  = 768;
constexpr int DI  = 1536;
constexpr int DS  = 16;
constexpr int DC  = 4;
constexpr int DR  = 48;
constexpr int M   = Bc * Lc;          // 16384 rows
constexpr int NC  = 32;               // scan chunks (measured optimum; NC=16 regressed)
constexpr int CT  = Lc / NC;          // 64 timesteps per chunk
constexpr float EPS_ = 1e-5f;

typedef __bf16 bf16x8 __attribute__((ext_vector_type(8)));
typedef float  f32x4  __attribute__((ext_vector_type(4)));

__device__ __forceinline__ float siluf(float x) { return x / (1.f + __expf(-x)); }
__device__ __forceinline__ float softplusf(float x) {
  return (x > 20.f) ? x : __logf(1.f + __expf(x));
}

#define GLOAD16(gp, lp)                                                        \
  __builtin_amdgcn_global_load_lds(                                            \
      (const __attribute__((address_space(1))) void*)(gp),                     \
      (__attribute__((address_space(3))) void*)(lp), 16, 0, 0)

// -------- f32 -> bf16 conversion (packed) --------
__global__ __launch_bounds__(256) void k_f2b(const float* __restrict__ in,
                                             __bf16* __restrict__ out, int n4) {
  for (int i = blockIdx.x * 256 + threadIdx.x; i < n4; i += gridDim.x * 256) {
    float4 v = *(const float4*)(in + (size_t)i * 4);
    __bf16* o = out + (size_t)i * 4;
    o[0] = (__bf16)v.x; o[1] = (__bf16)v.y; o[2] = (__bf16)v.z; o[3] = (__bf16)v.w;
  }
}

// f32 -> bf16 with per-layer row/col zero-padding.
__global__ __launch_bounds__(256) void k_f2b_pad(const float* __restrict__ in,
                                                 __bf16* __restrict__ out,
                                                 int layers, int rin, int rout,
                                                 int cin, int cout) {
  size_t total = (size_t)layers * rout * cout;
  for (size_t i = (size_t)blockIdx.x * 256 + threadIdx.x; i < total;
       i += (size_t)gridDim.x * 256) {
    int lay = (int)(i / ((size_t)rout * cout));
    int rem = (int)(i % ((size_t)rout * cout));
    int r = rem / cout, c = rem % cout;
    float v = (r < rin && c < cin) ? in[((size_t)lay * rin + r) * cin + c] : 0.f;
    out[i] = (__bf16)v;
  }
}

// h[row,d] = embed[ids[row]][d] + times[row]*time_w[d] + time_b[d]   (bf16 h)
__global__ void k_embed(const int* __restrict__ ids, const float* __restrict__ times,
                        const float* __restrict__ emb, const float* __restrict__ tw,
                        const float* __restrict__ tb, __bf16* __restrict__ h) {
  int row = blockIdx.x;
  int id  = ids[row];
  float tv = times[row];
  const float* e = emb + (size_t)id * DM;
  for (int d = threadIdx.x; d < DM; d += blockDim.x)
    h[(size_t)row * DM + d] = (__bf16)(e[d] + tv * tw[d] + tb[d]);
}

// bf16 in/out: o[row,:] = h[row,:] * rsqrt(mean(h^2)+eps) * w
__global__ __launch_bounds__(256) void k_rmsnorm(const __bf16* __restrict__ x,
                                                 const float* __restrict__ w,
                                                 __bf16* __restrict__ o) {
  int row = blockIdx.x;
  const __bf16* xr = x + (size_t)row * DM;
  float v[3];
  float s = 0.f;
#pragma unroll
  for (int i = 0; i < 3; i++) { v[i] = (float)xr[threadIdx.x + 256 * i]; s += v[i] * v[i]; }
#pragma unroll
  for (int off = 32; off > 0; off >>= 1) s += __shfl_down(s, off);
  __shared__ float red[4];
  int lane = threadIdx.x & 63, wv = threadIdx.x >> 6;
  if (lane == 0) red[wv] = s;
  __syncthreads();
  if (threadIdx.x == 0)
    red[0] = rsqrtf((red[0] + red[1] + red[2] + red[3]) / (float)DM + EPS_);
  __syncthreads();
  float sc = red[0];
#pragma unroll
  for (int i = 0; i < 3; i++) {
    int d = threadIdx.x + 256 * i;
    o[(size_t)row * DM + d] = (__bf16)(v[i] * sc * w[d]);
  }
}

// Depthwise causal conv (width 4) + bias + silu ; bf16x8 vectorized, dense [M][DI].
__global__ __launch_bounds__(256) void k_conv8(const __bf16* __restrict__ xb,
                                               const float* __restrict__ cwt,
                                               const float* __restrict__ cbv,
                                               __bf16* __restrict__ xo) {
  size_t idx = (size_t)blockIdx.x * 256 + threadIdx.x;   // < M*DI/8
  int dg = (int)(idx % (DI / 8));
  size_t row = idx / (DI / 8);
  int d0 = dg * 8;
  int t = (int)(row % Lc);
  size_t b = row / Lc;
  float acc[8];
  float4 cwv[8];
#pragma unroll
  for (int j = 0; j < 8; j++) {
    acc[j] = cbv[d0 + j];
    cwv[j] = *(const float4*)(cwt + (d0 + j) * DC);
  }
#pragma unroll
  for (int tap = 0; tap < DC; tap++) {
    int tt = t - (DC - 1) + tap;
    if (tt >= 0) {
      bf16x8 v = *(const bf16x8*)(xb + ((size_t)b * Lc + tt) * DI + d0);
#pragma unroll
      for (int j = 0; j < 8; j++) {
        float wt = (tap == 0) ? cwv[j].x : (tap == 1) ? cwv[j].y
                   : (tap == 2) ? cwv[j].z : cwv[j].w;
        acc[j] += wt * (float)v[j];
      }
    }
  }
  bf16x8 o;
#pragma unroll
  for (int j = 0; j < 8; j++) o[j] = (__bf16)siluf(acc[j]);
  *(bf16x8*)(xo + idx * 8) = o;
}

// ------ bf16 MFMA GEMM: 128x256 tile, BK=32, 512 threads, 2-phase LDS dbuf ------
// Session-converged optimum (see R24 notes); unchanged.
__global__ __launch_bounds__(512) void k_gemm_mfma(
    const __bf16* __restrict__ A, int lda,
    const __bf16* __restrict__ W, int ldw,
    const float* __restrict__ bias,
    float* __restrict__ Cf, __bf16* __restrict__ Cb, int ldc,
    int N, int K, int act, int resAdd,
    __bf16* __restrict__ Cb2, int Nsplit) {
  constexpr int BUFE = 12288;           // A 4096 + B 8192 elements per buffer
  __shared__ __bf16 lds[2 * BUFE];      // 48 KB
  int tid = threadIdx.x;
  int l = tid & 63, w = tid >> 6;       // 8 waves
  int wr = w >> 2, wc = w & 3;          // 2 M-halves x 4 N-quarters

  // L2-aware sub-chunked remap: XCD (lin&7) owns bm-blocks [xcd*cm, xcd*cm+cm);
  // within it, iterate all bn for 4 bm-blocks at a time (A sub-panel 1.18MB).
  int gm = gridDim.x;                   // # of 128-row bm blocks
  int nb = gridDim.y;                   // # of 256-col bn blocks
  int lin = blockIdx.y * gm + blockIdx.x;
  int cm = gm >> 3;                     // bm-blocks per XCD chunk (16)
  int xcd = lin & 7;
  int r = lin >> 3;                     // [0, cm*nb)
  int subi = r / (nb << 2);             // sub-chunk index (cm/4 of them)
  int rem  = r % (nb << 2);
  int bni  = rem >> 2;
  int bmj  = rem & 3;
  int bm = (xcd * cm + subi * 4 + bmj) << 7;
  int bn = bni << 8;                    // 256-wide N tiles

  // --- staging: A 512 chunks (1/thread), B 1024 chunks (2/thread); 16B each.
  int ra0 = 16 * w + (l >> 2);
  int rb0 = ra0;
  int rb1 = 128 + ra0;
  int sa0 = ((l & 3) - ra0 - (ra0 >> 2)) & 3;   // pre-permuted global k-slot
  int sb0 = sa0;
  int sb1 = ((l & 3) - rb1 - (rb1 >> 2)) & 3;
  const char* gA0 = (const char*)(A + (size_t)(bm + ra0) * lda) + sa0 * 16;
  const char* gB0 = (const char*)(W + (size_t)(bn + rb0) * ldw) + sb0 * 16;
  const char* gB1 = (const char*)(W + (size_t)(bn + rb1) * ldw) + sb1 * 16;
  int lA0 = (16 * w) * 32;                      // element offsets inside a buffer
  int lB0 = 4096 + (16 * w) * 32;
  int lB1 = 4096 + (128 + 16 * w) * 32;

  int aoff[4], boff[4];
#pragma unroll
  for (int i = 0; i < 4; i++) {
    int ra = wr * 64 + i * 16 + (l & 15);
    aoff[i] = ra * 32 + ((((l >> 4) + ra + (ra >> 2)) & 3) << 3);
    int rb = wc * 64 + i * 16 + (l & 15);
    boff[i] = 4096 + rb * 32 + ((((l >> 4) + rb + (rb >> 2)) & 3) << 3);
  }

  f32x4 acc[4][4];
#pragma unroll
  for (int i = 0; i < 4; i++)
#pragma unroll
    for (int j = 0; j < 4; j++)
#pragma unroll
      for (int e = 0; e < 4; e++) acc[i][j][e] = 0.f;

#define STAGE(t)                                                               \
  do {                                                                         \
    __bf16* Lb_ = lds + ((t) & 1) * BUFE;                                      \
    size_t kb_ = (size_t)(t) * 64;                                             \
    GLOAD16(gA0 + kb_, Lb_ + lA0);                                             \
    GLOAD16(gB0 + kb_, Lb_ + lB0);                                             \
    GLOAD16(gB1 + kb_, Lb_ + lB1);                                             \
  } while (0)

  int NT = K >> 5;
  STAGE(0);
  __syncthreads();                      // drain tile 0

  for (int t = 0; t < NT; ++t) {
    if (t + 1 < NT) STAGE(t + 1);       // async: in flight during compute of tile t
    const __bf16* Lb = lds + (t & 1) * BUFE;
    bf16x8 af[4], bfr[4];
#pragma unroll
    for (int i = 0; i < 4; i++) {
      af[i]  = *(const bf16x8*)(Lb + aoff[i]);
      bfr[i] = *(const bf16x8*)(Lb + boff[i]);
    }
    __builtin_amdgcn_s_setprio(1);
#pragma unroll
    for (int i = 0; i < 4; i++)
#pragma unroll
      for (int j = 0; j < 4; j++)
        acc[i][j] = __builtin_amdgcn_mfma_f32_16x16x32_bf16(af[i], bfr[j], acc[i][j], 0, 0, 0);
    __builtin_amdgcn_s_setprio(0);
    __syncthreads();                    // drains stage(t+1) + barrier (one per tile)
  }
#undef STAGE

#pragma unroll
  for (int i = 0; i < 4; i++) {
#pragma unroll
    for (int r2 = 0; r2 < 4; r2++) {
      int grow = bm + wr * 64 + i * 16 + (l >> 4) * 4 + r2;
#pragma unroll
      for (int j = 0; j < 4; j++) {
        int gcol = bn + wc * 64 + j * 16 + (l & 15);
        if (gcol < N) {
          float v = acc[i][j][r2];
          if (bias) v += bias[gcol];
          if (act == 1) v = softplusf(v);
          size_t off = (size_t)grow * ldc + gcol;
          if (Cb2) {
            if (gcol < Nsplit) Cb[off] = (__bf16)v;
            else               Cb2[(size_t)grow * ldc + (gcol - Nsplit)] = (__bf16)v;
          } else if (Cb) {
            if (resAdd) Cb[off] = (__bf16)((float)Cb[off] + v);
            else        Cb[off] = (__bf16)v;
          } else if (resAdd) {
            Cf[off] += v;
          } else {
            Cf[off] = v;
          }
        }
      }
    }
  }
}

// ---------------- chunked selective scan ----------------
// sc is bf16: [h0..h15 | P0..P15] per (b,c,d).  A_log fast path: Av[n] = -(n+1)
// (detected per-thread, exact fallback otherwise).
__global__ __launch_bounds__(256) void k_scan1(
    const __bf16* __restrict__ dlt,
    const __bf16* __restrict__ u_xc,
    const __bf16* __restrict__ xdbl,
    const float* __restrict__ alog,
    __bf16* __restrict__ sc) {
  __shared__ float bcs[CT][32];
  int b = blockIdx.z, c = blockIdx.y;
  int d = blockIdx.x * 256 + threadIdx.x;
  int row0 = b * Lc + c * CT;
#pragma unroll
  for (int k = 0; k < (CT * 32) / 256; k++) {
    int i = k * 256 + threadIdx.x;
    int t = i >> 5, j = i & 31;
    bcs[t][j] = (float)xdbl[(size_t)(row0 + t) * 80 + 48 + j];
  }
  float Av[16];
#pragma unroll
  for (int n = 0; n < 16; n++) Av[n] = -__expf(alog[d * DS + n]);
  bool fast = true;
#pragma unroll
  for (int n = 0; n < 16; n++) fast = fast && (fabsf(Av[n] + (float)(n + 1)) < 1e-4f);
  float h[16], P[16];
#pragma unroll
  for (int n = 0; n < 16; n++) { h[n] = 0.f; P[n] = 1.f; }
  float S = 0.f;
  __syncthreads();
  if (fast) {
    for (int t = 0; t < CT; t++) {
      size_t row = row0 + t;
      float dl = (float)dlt[row * DI + d];
      float u  = (float)u_xc[row * DI + d];
      float du = dl * u;
      float e[16];
      e[0] = __expf(-dl);
#pragma unroll
      for (int n = 1; n < 16; n++) e[n] = e[n - 1] * e[0];
#pragma unroll
      for (int n = 0; n < 16; n++) h[n] = h[n] * e[n] + du * bcs[t][n];
      S += dl;
    }
    P[0] = __expf(-S);
#pragma unroll
    for (int n = 1; n < 16; n++) P[n] = P[n - 1] * P[0];
  } else {
    for (int t = 0; t < CT; t++) {
      size_t row = row0 + t;
      float dl = (float)dlt[row * DI + d];
      float u  = (float)u_xc[row * DI + d];
      float du = dl * u;
#pragma unroll
      for (int n = 0; n < 16; n++) {
        float e = __expf(dl * Av[n]);
        h[n] = h[n] * e + du * bcs[t][n];
        P[n] *= e;
      }
    }
  }
  __bf16* o = sc + (((size_t)b * NC + c) * DI + d) * 32;
  bf16x8 v0, v1, v2, v3;
#pragma unroll
  for (int n = 0; n < 8; n++) { v0[n] = (__bf16)h[n]; v1[n] = (__bf16)h[8 + n];
                                v2[n] = (__bf16)P[n]; v3[n] = (__bf16)P[8 + n]; }
  *(bf16x8*)(o)      = v0;
  *(bf16x8*)(o + 8)  = v1;
  *(bf16x8*)(o + 16) = v2;
  *(bf16x8*)(o + 24) = v3;
}

// Pass 2: batch the 32 chunk loads up front (independent -> one latency
// exposure), run the 32-step recurrence in registers, then write back h_in.
__global__ __launch_bounds__(256) void k_scan2(__bf16* __restrict__ sc) {
  int g = blockIdx.x * 256 + threadIdx.x;
  int n = g & 15;
  int rest = g >> 4;
  int d = rest % DI;
  int b = rest / DI;
  __bf16* base = sc + ((size_t)b * NC * DI + d) * 32;
  constexpr size_t CSTRIDE = (size_t)DI * 32;   // elements between chunks
  float hf[NC], pd[NC];
#pragma unroll
  for (int c = 0; c < NC; c++) {
    const __bf16* p = base + c * CSTRIDE;
    hf[c] = (float)p[n];
    pd[c] = (float)p[16 + n];
  }
  float cur = 0.f;
#pragma unroll
  for (int c = 0; c < NC; c++) {
    base[c * CSTRIDE + n] = (__bf16)cur;
    cur = pd[c] * cur + hf[c];
  }
}

__global__ __launch_bounds__(256) void k_scan3(
    const __bf16* __restrict__ dlt,
    const __bf16* __restrict__ zb,
    __bf16* __restrict__ u_xc,          // in: u, out: y*silu(z)
    const __bf16* __restrict__ xdbl,
    const float* __restrict__ alog,
    const float* __restrict__ dsk,
    const __bf16* __restrict__ sc) {
  __shared__ float bcs[CT][32];
  int b = blockIdx.z, c = blockIdx.y;
  int d = blockIdx.x * 256 + threadIdx.x;
  int row0 = b * Lc + c * CT;
#pragma unroll
  for (int k = 0; k < (CT * 32) / 256; k++) {
    int i = k * 256 + threadIdx.x;
    int t = i >> 5, j = i & 31;
    bcs[t][j] = (float)xdbl[(size_t)(row0 + t) * 80 + 48 + j];
  }
  float Av[16];
#pragma unroll
  for (int n = 0; n < 16; n++) Av[n] = -__expf(alog[d * DS + n]);
  bool fast = true;
#pragma unroll
  for (int n = 0; n < 16; n++) fast = fast && (fabsf(Av[n] + (float)(n + 1)) < 1e-4f);
  float Dv = dsk[d];
  float h[16];
  const __bf16* ip = sc + (((size_t)b * NC + c) * DI + d) * 32;
  {
    bf16x8 v0 = *(const bf16x8*)(ip);
    bf16x8 v1 = *(const bf16x8*)(ip + 8);
#pragma unroll
    for (int n = 0; n < 8; n++) { h[n] = (float)v0[n]; h[8 + n] = (float)v1[n]; }
  }
  __syncthreads();
  if (fast) {
    for (int t = 0; t < CT; t++) {
      size_t row = row0 + t;
      float dl = (float)dlt[row * DI + d];
      float u  = (float)u_xc[row * DI + d];
      float du = dl * u;
      float e[16];
      e[0] = __expf(-dl);
#pragma unroll
      for (int n = 1; n < 16; n++) e[n] = e[n - 1] * e[0];
      float y = 0.f;
#pragma unroll
      for (int n = 0; n < 16; n++) {
        h[n] = h[n] * e[n] + du * bcs[t][n];
        y += h[n] * bcs[t][16 + n];
      }
      y += u * Dv;
      float z = (float)zb[row * DI + d];
      u_xc[row * DI + d] = (__bf16)(y * siluf(z));
    }
  } else {
    for (int t = 0; t < CT; t++) {
      size_t row = row0 + t;
      float dl = (float)dlt[row * DI + d];
      float u  = (float)u_xc[row * DI + d];
      float du = dl * u;
      float y = 0.f;
#pragma unroll
      for (int n = 0; n < 16; n++) {
        float e = __expf(dl * Av[n]);
        h[n] = h[n] * e + du * bcs[t][n];
        y += h[n] * bcs[t][16 + n];
      }
      y += u * Dv;
      float z = (float)zb[row * DI + d];
      u_xc[row * DI + d] = (__bf16)(y * siluf(z));
    }
  }
}

}  // namespace

extern "C" void kernel_launch(void* const* d_in, const int* in_sizes, int n_in,
                              void* d_out, int out_size, void* d_ws, size_t ws_size,
                              hipStream_t stream) {
  const int*   ids   = (const int*)d_in[0];
  const float* times = (const float*)d_in[1];
  const float* emb   = (const float*)d_in[3];
  const float* tw    = (const float*)d_in[4];
  const float* tb    = (const float*)d_in[5];
  const float* inw   = (const float*)d_in[6];
  const float* cw    = (const float*)d_in[7];
  const float* cb    = (const float*)d_in[8];
  const float* xw    = (const float*)d_in[9];
  const float* dtw   = (const float*)d_in[10];
  const float* dtb   = (const float*)d_in[11];
  const float* alog  = (const float*)d_in[12];
  const float* dsk   = (const float*)d_in[13];
  const float* ow    = (const float*)d_in[14];
  const float* nw    = (const float*)d_in[15];
  const float* nfw   = (const float*)d_in[16];
  float* out = (float*)d_out;

  // ---- workspace layout (bf16; 16B aligned) ----
  __bf16* wsb = (__bf16*)d_ws;
  __bf16* hb    = wsb;  wsb += (size_t)M * DM;               // 25.2 MB (bf16 residual)
  __bf16* hnb   = wsb;  wsb += (size_t)M * DM;               // 25.2 MB
  __bf16* xb    = wsb;  wsb += (size_t)M * DI;               // 50.3 MB
  __bf16* zbuf  = wsb;  wsb += (size_t)M * DI;               // 50.3 MB
  __bf16* xcb   = wsb;  wsb += (size_t)M * DI;               // 50.3 MB
  __bf16* dltb  = wsb;  wsb += (size_t)M * DI;               // 50.3 MB (bf16 delta)
  __bf16* scb   = wsb;  wsb += (size_t)Bc * NC * DI * 32;    // 25.2 MB (bf16 chunk states)
  __bf16* xdblb = wsb;  wsb += (size_t)M * 80;               // 2.6 MB
  __bf16* ebw   = wsb;  wsb += (size_t)VOCP * DM;            // 3.1 MB
  __bf16* inwb  = wsb;  wsb += (size_t)4 * 2 * DI * DM;      // 18.9 MB
  __bf16* xwb   = wsb;  wsb += (size_t)4 * 256 * DI;         // 3.1 MB (80->256 rows)
  __bf16* owb   = wsb;  wsb += (size_t)4 * DM * DI;          // 9.4 MB
  __bf16* dtwb  = wsb;  wsb += (size_t)4 * DI * 64;          // 0.8 MB

  // weight / embed conversions (every call; deterministic)
  k_f2b<<<2048, 256, 0, stream>>>(inw, inwb, (4 * 2 * DI * DM) / 4);
  k_f2b<<<2048, 256, 0, stream>>>(ow,  owb,  (4 * DM * DI) / 4);
  k_f2b_pad<<<2048, 256, 0, stream>>>(emb, ebw, 1, VOC, VOCP, DM, DM);
  k_f2b_pad<<<2048, 256, 0, stream>>>(xw,  xwb, 4, 80, 256, DI, DI);
  k_f2b_pad<<<1024, 256, 0, stream>>>(dtw, dtwb, 4, DI, DI, DR, 64);

  k_embed<<<M, 256, 0, stream>>>(ids, times, emb, tw, tb, hb);

  for (int i = 0; i < 4; i++) {
    k_rmsnorm<<<M, 256, 0, stream>>>(hb, nw + i * DM, hnb);
    {  // [x | z] = hn @ in_proj^T  (ONE dispatch, split bf16 outputs xb / zbuf)
      dim3 g(M / 128, (2 * DI) / 256);
      k_gemm_mfma<<<g, 512, 0, stream>>>(hnb, DM, inwb + (size_t)i * 2 * DI * DM, DM,
                                         nullptr, nullptr, xb, DI, 2 * DI, DM, 0, 0,
                                         zbuf, DI);
    }
    {  // xcb = silu(conv1d(x) + cb)   (vectorized, 8 d's per thread)
      int blocks = (int)(((size_t)M * DI / 8) / 256);
      k_conv8<<<blocks, 256, 0, stream>>>(xb, cw + i * DI * DC, cb + i * DI, xcb);
    }
    {  // xdbl = u @ x_proj^T  (bf16 out, N=80, weights padded to 256 rows)
      dim3 g(M / 128, 1);
      k_gemm_mfma<<<g, 512, 0, stream>>>(xcb, DI, xwb + (size_t)i * 256 * DI, DI,
                                         nullptr, nullptr, xdblb, 80, 80, DI, 0, 0,
                                         nullptr, 0);
    }
    {  // delta = softplus(xdbl @ dtw_pad^T + dtb)  -> bf16 (K=64)
      dim3 g(M / 128, DI / 256);
      k_gemm_mfma<<<g, 512, 0, stream>>>(xdblb, 80, dtwb + (size_t)i * DI * 64, 64,
                                         dtb + i * DI, nullptr, dltb, DI, DI, 64, 1, 0,
                                         nullptr, 0);
    }
    {  // chunked selective scan + y*silu(z), in place over xcb
      dim3 g1(DI / 256, NC, Bc);
      k_scan1<<<g1, 256, 0, stream>>>(dltb, xcb, xdblb, alog + (size_t)i * DI * DS, scb);
      k_scan2<<<(Bc * DI * DS) / 256, 256, 0, stream>>>(scb);
      k_scan3<<<g1, 256, 0, stream>>>(dltb, zbuf, xcb, xdblb,
                                      alog + (size_t)i * DI * DS, dsk + i * DI, scb);
    }
    {  // h += y @ out_proj^T   (bf16 RMW resAdd)
      dim3 g(M / 128, DM / 256);
      k_gemm_mfma<<<g, 512, 0, stream>>>(xcb, DI, owb + (size_t)i * DM * DI, DI,
                                         nullptr, nullptr, hb, DM, DM, DI, 0, 1,
                                         nullptr, 0);
    }
  }

  k_rmsnorm<<<M, 256, 0, stream>>>(hb, nfw, hnb);
  {  // logits = hn @ embed^T   (N=1969, padded rows, f32 out)
    dim3 g(M / 128, VOCP / 256);
    k_gemm_mfma<<<g, 512, 0, stream>>>(hnb, DM, ebw, DM,
                                       nullptr, out, nullptr, VOC, VOC, DM, 0, 0,
                                       nullptr, 0);
  }
}